// Round 8
// baseline (388.225 us; speedup 1.0000x reference)
//
#include <hip/hip_runtime.h>
#include <hip/hip_bf16.h>
#include <math.h>

#define NN 150000
#define EE 600000
#define GG 5000
#define NI 16
#define EI 8
#define GFD 32
#define HH 64
#define CC 40

#define W2ROW 1088   // 68 chunks * 16 (64 real + bias + 3 zero-pad for 4-deep prefetch)
#define EHS 72       // u16 stride of eh rows: 144B = 16B-aligned, 4-way max bank spread
#define FPAD 68
#define NBLK ((NN + 1023) / 1024)

typedef __attribute__((ext_vector_type(8))) short short8v;
typedef __attribute__((ext_vector_type(8))) unsigned short ushort8v;
typedef __attribute__((ext_vector_type(16))) float f32x16;

__device__ __forceinline__ unsigned short f2bf(float f) {
    __hip_bfloat16 h = __float2bfloat16(f);
    return __builtin_bit_cast(unsigned short, h);
}
__device__ __forceinline__ float bf2f(unsigned short u) {
    return __uint_as_float(((unsigned)u) << 16);
}
__device__ __forceinline__ unsigned cvtpk(float lo, float hi) {
    unsigned r;
    asm("v_cvt_pk_bf16_f32 %0, %1, %2" : "=v"(r) : "v"(lo), "v"(hi));
    return r;
}
__device__ __forceinline__ short8v zfrag(float eh, const float (&xs)[8]) {
    union { short8v v; unsigned u[4]; } A;
    #pragma unroll
    for (int q = 0; q < 4; ++q)
        A.u[q] = cvtpk(eh * xs[2 * q], eh * xs[2 * q + 1]);
    return A.v;
}
__device__ __forceinline__ short8v xfrag(const float (&xs)[8]) {
    union { short8v v; unsigned u[4]; } A;
    #pragma unroll
    for (int q = 0; q < 4; ++q)
        A.u[q] = cvtpk(xs[2 * q], xs[2 * q + 1]);
    return A.v;
}

// ---------------- K0: prep bf16 weight views ----------------
__global__ void k0_prep(const float* __restrict__ W_e2, const float* __restrict__ b_e2,
                        const float* __restrict__ W_fc1, const float* __restrict__ W_np,
                        unsigned short* __restrict__ W2T,
                        unsigned short* __restrict__ W1aT,
                        unsigned short* __restrict__ W_npT)
{
    int idx = blockIdx.x * 256 + threadIdx.x;
    if (idx < 64 * W2ROW) {
        int h = idx / W2ROW, j = idx % W2ROW;
        float v = 0.f;
        if (j < 1024)      { int k = j >> 4, i = j & 15; v = W_e2[k * 1024 + i * 64 + h]; }
        else if (j < 1040) { int i = j - 1024;           v = b_e2[i * 64 + h]; }
        W2T[idx] = f2bf(v);
    } else if (idx < 64 * W2ROW + 4096) {
        int i = idx - 64 * W2ROW;
        int h = i >> 6, k = i & 63;
        W1aT[i] = f2bf(W_fc1[k * 64 + h]);
    } else if (idx < 64 * W2ROW + 8192) {
        int i = idx - 64 * W2ROW - 4096;
        int c = i >> 6, h = i & 63;
        W_npT[i] = f2bf(c < CC ? W_np[h * CC + c] : 0.f);
    }
}

// ---------------- counting sort (rank only) ----------------
__global__ void kA_hist(const int* __restrict__ ei, int* __restrict__ cnt)
{
    int e = blockIdx.x * 256 + threadIdx.x;
    if (e < EE) atomicAdd(&cnt[ei[EE + e]], 1);
}

__global__ void kB_scan1(const int* __restrict__ cnt, int* __restrict__ base,
                         int* __restrict__ bsum)
{
    __shared__ int sS[256];
    int b = blockIdx.x, t = threadIdx.x;
    int i0 = b * 1024 + t * 4;
    int v0 = (i0 + 0 < NN) ? cnt[i0 + 0] : 0;
    int v1 = (i0 + 1 < NN) ? cnt[i0 + 1] : 0;
    int v2 = (i0 + 2 < NN) ? cnt[i0 + 2] : 0;
    int v3 = (i0 + 3 < NN) ? cnt[i0 + 3] : 0;
    int tot = v0 + v1 + v2 + v3;
    sS[t] = tot;
    __syncthreads();
    int acc = tot;
    for (int off = 1; off < 256; off <<= 1) {
        int xv = (t >= off) ? sS[t - off] : 0;
        __syncthreads();
        acc += xv;
        sS[t] = acc;
        __syncthreads();
    }
    int run = acc - tot;
    if (i0 + 0 < NN) base[i0 + 0] = run; run += v0;
    if (i0 + 1 < NN) base[i0 + 1] = run; run += v1;
    if (i0 + 2 < NN) base[i0 + 2] = run; run += v2;
    if (i0 + 3 < NN) base[i0 + 3] = run;
    if (t == 255) bsum[b] = acc;
}

__global__ void kC_scan2(int* __restrict__ bsum)
{
    __shared__ int sS[256];
    int t = threadIdx.x;
    int v = (t < NBLK) ? bsum[t] : 0;
    sS[t] = v;
    __syncthreads();
    int acc = v;
    for (int off = 1; off < 256; off <<= 1) {
        int xv = (t >= off) ? sS[t - off] : 0;
        __syncthreads();
        acc += xv;
        sS[t] = acc;
        __syncthreads();
    }
    if (t < NBLK) bsum[t] = acc - v;   // exclusive
}

__global__ void kD_scan3(int* __restrict__ base, const int* __restrict__ bsum,
                         int* __restrict__ cursor)
{
    int i = blockIdx.x * 256 + threadIdx.x;
    if (i < NN) {
        int v = base[i] + bsum[i >> 10];
        base[i] = v;
        cursor[i] = v;
    }
    if (i == 0) base[NN] = EE;
}

__global__ void kE_rank(const int* __restrict__ ei, int* __restrict__ cursor,
                        int* __restrict__ rank)
{
    int e = blockIdx.x * 256 + threadIdx.x;
    if (e < EE) {
        int d = ei[EE + e];
        rank[e] = atomicAdd(&cursor[d], 1);
    }
}

// ---------------- MFMA inner step: consume prefetched B, refill 4-deep ----------------
__device__ __forceinline__ void mfma_step2(
    float eh0, float eh1,
    const unsigned short* __restrict__ Bc0, const unsigned short* __restrict__ Bc1,
    int pfu,  // static u16 offset of the prefetch chunk
    const float (&xs0)[8], const float (&xs1)[8],
    short8v& pb0, short8v& pb1,
    f32x16& acc00, f32x16& acc01, f32x16& acc10, f32x16& acc11)
{
    short8v n0 = *(const short8v*)(Bc0 + pfu);
    short8v n1 = *(const short8v*)(Bc1 + pfu);
    short8v a0 = zfrag(eh0, xs0);
    short8v a1 = zfrag(eh1, xs1);
    __builtin_amdgcn_s_setprio(1);
    acc00 = __builtin_amdgcn_mfma_f32_32x32x16_bf16(a0, pb0, acc00, 0, 0, 0);
    acc01 = __builtin_amdgcn_mfma_f32_32x32x16_bf16(a0, pb1, acc01, 0, 0, 0);
    acc10 = __builtin_amdgcn_mfma_f32_32x32x16_bf16(a1, pb0, acc10, 0, 0, 0);
    acc11 = __builtin_amdgcn_mfma_f32_32x32x16_bf16(a1, pb1, acc11, 0, 0, 0);
    __builtin_amdgcn_s_setprio(0);
    pb0 = n0; pb1 = n1;
}

// ---------------- K1: edge MLP + MFMA z-GEMM; TWOPHASE: bf16 paired store, else atomic ----------------
template<bool TWOPHASE>
__global__ __launch_bounds__(256, 3) void k1_mfma(
    const float* __restrict__ x, const int* __restrict__ ei,
    const float* __restrict__ ea,
    const float* __restrict__ W_e1, const float* __restrict__ b_e1,
    const unsigned short* __restrict__ W2T,
    const int* __restrict__ rank,
    unsigned* __restrict__ msg16, float* __restrict__ agg)
{
    __shared__ __align__(16) unsigned short sEHT2[256][EHS];   // [edge][chunk] bf16
    __shared__ int sIdx[256];

    const int t = threadIdx.x;
    const long long eb = (long long)blockIdx.x * 256;

    {
        long long ge = eb + t;
        sIdx[t] = (ge < EE) ? (TWOPHASE ? rank[ge] : ei[EE + ge]) : -1;
    }

    // ---- edge MLP layer 1 -> sEHT2[e][k], u32 k-pair writes via cvt_pk ----
    {
        const int kp = t & 31;       // k-pair: cols 2kp, 2kp+1
        const int eg = t >> 5;       // edge group of 32
        float w1a[8], w1b[8];
        float b1a = b_e1[2 * kp], b1b = b_e1[2 * kp + 1];
        #pragma unroll
        for (int j = 0; j < 8; ++j) {
            w1a[j] = W_e1[j * 64 + 2 * kp];
            w1b[j] = W_e1[j * 64 + 2 * kp + 1];
        }
        #pragma unroll 4
        for (int r = 0; r < 32; ++r) {
            int e = eg * 32 + r;
            long long gee = eb + e;
            float va = 0.f, vb = 0.f;
            if (gee < EE) {
                const float4* eap = (const float4*)(ea + gee * EI);
                float4 u0 = eap[0], u1 = eap[1];
                va = b1a; vb = b1b;
                va = fmaf(u0.x, w1a[0], va); vb = fmaf(u0.x, w1b[0], vb);
                va = fmaf(u0.y, w1a[1], va); vb = fmaf(u0.y, w1b[1], vb);
                va = fmaf(u0.z, w1a[2], va); vb = fmaf(u0.z, w1b[2], vb);
                va = fmaf(u0.w, w1a[3], va); vb = fmaf(u0.w, w1b[3], vb);
                va = fmaf(u1.x, w1a[4], va); vb = fmaf(u1.x, w1b[4], vb);
                va = fmaf(u1.y, w1a[5], va); vb = fmaf(u1.y, w1b[5], vb);
                va = fmaf(u1.z, w1a[6], va); vb = fmaf(u1.z, w1b[6], vb);
                va = fmaf(u1.w, w1a[7], va); vb = fmaf(u1.w, w1b[7], vb);
                va = fmaxf(va, 0.f); vb = fmaxf(vb, 0.f);
            }
            *(unsigned*)&sEHT2[e][2 * kp] = cvtpk(va, vb);
        }
    }

    const int lane = t & 63;
    const int w = t >> 6;
    const int mr = lane & 31;
    const int half = lane >> 5;
    const int mb = w * 64;

    // ---- per-lane xs gather ----
    float xs0[8], xs1[8];
    {
        long long e0g = eb + mb + mr;
        long long e1g = eb + mb + 32 + mr;
        if (e0g < EE) {
            int s0 = ei[e0g];
            const float4* xp = (const float4*)(x + (size_t)s0 * NI + half * 8);
            float4 u0 = xp[0], u1 = xp[1];
            xs0[0]=u0.x; xs0[1]=u0.y; xs0[2]=u0.z; xs0[3]=u0.w;
            xs0[4]=u1.x; xs0[5]=u1.y; xs0[6]=u1.z; xs0[7]=u1.w;
        } else {
            #pragma unroll
            for (int q = 0; q < 8; ++q) xs0[q] = 0.f;
        }
        if (e1g < EE) {
            int s1 = ei[e1g];
            const float4* xp = (const float4*)(x + (size_t)s1 * NI + half * 8);
            float4 u0 = xp[0], u1 = xp[1];
            xs1[0]=u0.x; xs1[1]=u0.y; xs1[2]=u0.z; xs1[3]=u0.w;
            xs1[4]=u1.x; xs1[5]=u1.y; xs1[6]=u1.z; xs1[7]=u1.w;
        } else {
            #pragma unroll
            for (int q = 0; q < 8; ++q) xs1[q] = 0.f;
        }
    }
    __syncthreads();

    f32x16 acc00, acc01, acc10, acc11;
    #pragma unroll
    for (int r = 0; r < 16; ++r) { acc00[r] = 0.f; acc01[r] = 0.f; acc10[r] = 0.f; acc11[r] = 0.f; }

    const unsigned short* Bq0 = W2T + (size_t)mr * W2ROW + half * 8;
    const unsigned short* Bq1 = Bq0 + 32 * W2ROW;

    // 4-deep B prefetch
    short8v P0a = *(const short8v*)(Bq0);
    short8v P0b = *(const short8v*)(Bq1);
    short8v P1a = *(const short8v*)(Bq0 + 16);
    short8v P1b = *(const short8v*)(Bq1 + 16);
    short8v P2a = *(const short8v*)(Bq0 + 32);
    short8v P2b = *(const short8v*)(Bq1 + 32);
    short8v P3a = *(const short8v*)(Bq0 + 48);
    short8v P3b = *(const short8v*)(Bq1 + 48);

    const int e0 = mb + mr, e1 = mb + 32 + mr;
    ushort8v ehA0 = *(const ushort8v*)&sEHT2[e0][0];
    ushort8v ehA1 = *(const ushort8v*)&sEHT2[e1][0];
    ushort8v ehB0, ehB1;

    #pragma unroll 1
    for (int cb = 0; cb < 64; cb += 16) {
        const unsigned short* Bc0 = Bq0 + cb * 16;
        const unsigned short* Bc1 = Bq1 + cb * 16;
        ehB0 = *(const ushort8v*)&sEHT2[e0][cb + 8];
        ehB1 = *(const ushort8v*)&sEHT2[e1][cb + 8];
        mfma_step2(bf2f(ehA0[0]), bf2f(ehA1[0]), Bc0, Bc1,  4*16, xs0, xs1, P0a, P0b, acc00, acc01, acc10, acc11);
        mfma_step2(bf2f(ehA0[1]), bf2f(ehA1[1]), Bc0, Bc1,  5*16, xs0, xs1, P1a, P1b, acc00, acc01, acc10, acc11);
        mfma_step2(bf2f(ehA0[2]), bf2f(ehA1[2]), Bc0, Bc1,  6*16, xs0, xs1, P2a, P2b, acc00, acc01, acc10, acc11);
        mfma_step2(bf2f(ehA0[3]), bf2f(ehA1[3]), Bc0, Bc1,  7*16, xs0, xs1, P3a, P3b, acc00, acc01, acc10, acc11);
        mfma_step2(bf2f(ehA0[4]), bf2f(ehA1[4]), Bc0, Bc1,  8*16, xs0, xs1, P0a, P0b, acc00, acc01, acc10, acc11);
        mfma_step2(bf2f(ehA0[5]), bf2f(ehA1[5]), Bc0, Bc1,  9*16, xs0, xs1, P1a, P1b, acc00, acc01, acc10, acc11);
        mfma_step2(bf2f(ehA0[6]), bf2f(ehA1[6]), Bc0, Bc1, 10*16, xs0, xs1, P2a, P2b, acc00, acc01, acc10, acc11);
        mfma_step2(bf2f(ehA0[7]), bf2f(ehA1[7]), Bc0, Bc1, 11*16, xs0, xs1, P3a, P3b, acc00, acc01, acc10, acc11);
        ehA0 = *(const ushort8v*)&sEHT2[e0][cb + 16];   // cb=48 reads cols 64..71 (pad, unused)
        ehA1 = *(const ushort8v*)&sEHT2[e1][cb + 16];
        mfma_step2(bf2f(ehB0[0]), bf2f(ehB1[0]), Bc0, Bc1, 12*16, xs0, xs1, P0a, P0b, acc00, acc01, acc10, acc11);
        mfma_step2(bf2f(ehB0[1]), bf2f(ehB1[1]), Bc0, Bc1, 13*16, xs0, xs1, P1a, P1b, acc00, acc01, acc10, acc11);
        mfma_step2(bf2f(ehB0[2]), bf2f(ehB1[2]), Bc0, Bc1, 14*16, xs0, xs1, P2a, P2b, acc00, acc01, acc10, acc11);
        mfma_step2(bf2f(ehB0[3]), bf2f(ehB1[3]), Bc0, Bc1, 15*16, xs0, xs1, P3a, P3b, acc00, acc01, acc10, acc11);
        mfma_step2(bf2f(ehB0[4]), bf2f(ehB1[4]), Bc0, Bc1, 16*16, xs0, xs1, P0a, P0b, acc00, acc01, acc10, acc11);
        mfma_step2(bf2f(ehB0[5]), bf2f(ehB1[5]), Bc0, Bc1, 17*16, xs0, xs1, P1a, P1b, acc00, acc01, acc10, acc11);
        mfma_step2(bf2f(ehB0[6]), bf2f(ehB1[6]), Bc0, Bc1, 18*16, xs0, xs1, P2a, P2b, acc00, acc01, acc10, acc11);
        mfma_step2(bf2f(ehB0[7]), bf2f(ehB1[7]), Bc0, Bc1, 19*16, xs0, xs1, P3a, P3b, acc00, acc01, acc10, acc11);
    }
    // bias chunk c=64: eh = 1 -> A = bf16(xs); B in P0
    {
        short8v a0 = xfrag(xs0);
        short8v a1 = xfrag(xs1);
        __builtin_amdgcn_s_setprio(1);
        acc00 = __builtin_amdgcn_mfma_f32_32x32x16_bf16(a0, P0a, acc00, 0, 0, 0);
        acc01 = __builtin_amdgcn_mfma_f32_32x32x16_bf16(a0, P0b, acc01, 0, 0, 0);
        acc10 = __builtin_amdgcn_mfma_f32_32x32x16_bf16(a1, P0a, acc10, 0, 0, 0);
        acc11 = __builtin_amdgcn_mfma_f32_32x32x16_bf16(a1, P0b, acc11, 0, 0, 0);
        __builtin_amdgcn_s_setprio(0);
    }

    // ---- epilogue ----
    #pragma unroll
    for (int r = 0; r < 16; ++r) {
        int row = (r & 3) + 8 * (r >> 2) + 4 * half;
        int i0 = sIdx[mb + row];
        int i1 = sIdx[mb + 32 + row];
        if (TWOPHASE) {
            if (i0 >= 0) msg16[(size_t)i0 * 32 + mr] = cvtpk(acc00[r], acc01[r]);
            if (i1 >= 0) msg16[(size_t)i1 * 32 + mr] = cvtpk(acc10[r], acc11[r]);
        } else {
            if (i0 >= 0) {
                atomicAdd(&agg[(size_t)i0 * 64 + mr],      acc00[r]);
                atomicAdd(&agg[(size_t)i0 * 64 + 32 + mr], acc01[r]);
            }
            if (i1 >= 0) {
                atomicAdd(&agg[(size_t)i1 * 64 + mr],      acc10[r]);
                atomicAdd(&agg[(size_t)i1 * 64 + 32 + mr], acc11[r]);
            }
        }
    }
}

// ---------------- K2 (two-phase): stream-reduce bf16 msg16 + mean + root + relu + gate ----------------
__global__ __launch_bounds__(256) void k2_red(
    const unsigned* __restrict__ msg16, const int* __restrict__ base,
    const float* __restrict__ x, const float* __restrict__ root,
    const float* __restrict__ conv_bias,
    float* __restrict__ hn,
    const float* __restrict__ Wg, const float* __restrict__ bg,
    float* __restrict__ gate)
{
    __shared__ float sroot[16][64];
    int t = threadIdx.x;
    #pragma unroll
    for (int q = 0; q < 4; ++q) {
        int i = q * 256 + t;
        sroot[i >> 6][i & 63] = root[i];
    }
    __syncthreads();

    int n = blockIdx.x * 4 + (t >> 6);
    int l = t & 63;
    int mr = l & 31, so = l >> 5;
    int s = base[n], e = base[n + 1];

    float alo = 0.f, ahi = 0.f;
    for (int sl = s + so; sl < e; sl += 2) {
        unsigned u = msg16[(size_t)sl * 32 + mr];
        alo += __uint_as_float(u << 16);
        ahi += __uint_as_float(u & 0xFFFF0000u);
    }
    alo += __shfl_xor(alo, 32);
    ahi += __shfl_xor(ahi, 32);
    float acc = (l < 32) ? alo : ahi;

    float inv = 1.0f / fmaxf((float)(e - s), 1.0f);
    float v = acc * inv + conv_bias[l];
    float xv = (l < 16) ? x[(size_t)n * NI + l] : 0.f;
    #pragma unroll
    for (int i = 0; i < 16; ++i)
        v = fmaf(__shfl(xv, i), sroot[i][l], v);
    v = fmaxf(v, 0.f);
    hn[(size_t)n * 64 + l] = v;

    float gv = v * Wg[l];
    #pragma unroll
    for (int off = 32; off; off >>= 1) gv += __shfl_xor(gv, off);
    if (l == 0) gate[n] = gv + bg[0];
}

// ---------------- K2 (fallback): mean + root + relu over agg ----------------
__global__ __launch_bounds__(256) void k2_node(
    const float* __restrict__ x, const float* __restrict__ root,
    const float* __restrict__ conv_bias, const int* __restrict__ cnt,
    float* __restrict__ hn,
    const float* __restrict__ Wg, const float* __restrict__ bg,
    float* __restrict__ gate)
{
    int t = threadIdx.x;
    int n = blockIdx.x * 4 + (t >> 6);
    int h = t & 63;
    float inv = 1.0f / fmaxf((float)cnt[n], 1.0f);
    float v = hn[(size_t)n * 64 + h] * inv + conv_bias[h];
    const float* xp = x + (size_t)n * NI;
    #pragma unroll
    for (int i = 0; i < NI; ++i) v += xp[i] * root[i * 64 + h];
    v = fmaxf(v, 0.f);
    hn[(size_t)n * 64 + h] = v;
    float gv = v * Wg[h];
    #pragma unroll
    for (int off = 32; off; off >>= 1) gv += __shfl_xor(gv, off);
    if (h == 0) gate[n] = gv + bg[0];
}

// ---------------- K3: per-graph pooling + pg/sg precompute ----------------
__device__ __forceinline__ int lbound(const int* __restrict__ b, int v) {
    int lo = 0, hi = NN;
    while (lo < hi) { int mid = (lo + hi) >> 1; if (b[mid] < v) lo = mid + 1; else hi = mid; }
    return lo;
}

__global__ __launch_bounds__(64) void k3_pool(
    const float* __restrict__ gate, const int* __restrict__ batch,
    const float* __restrict__ hn, const float* __restrict__ pocket,
    const float* __restrict__ W_fc1, const float* __restrict__ b_fc1,
    const float* __restrict__ W_sp, const float* __restrict__ b_sp,
    float* __restrict__ pg, float* __restrict__ sg)
{
    int g = blockIdx.x;
    int lane = threadIdx.x;
    int s = lbound(batch, g);
    int e = lbound(batch, g + 1);

    float gcv = 0.f;
    if (e > s) {
        float m = -INFINITY;
        for (int n = s + lane; n < e; n += 64) m = fmaxf(m, gate[n]);
        #pragma unroll
        for (int off = 32; off; off >>= 1) m = fmaxf(m, __shfl_xor(m, off));
        float acc = 0.f, den = 0.f;
        for (int n = s; n < e; ++n) {
            float ev = expf(gate[n] - m);
            den += ev;
            acc += ev * hn[(size_t)n * 64 + lane];
        }
        gcv = acc / den;
    }

    float sv = gcv * W_sp[lane];
    #pragma unroll
    for (int off = 32; off; off >>= 1) sv += __shfl_xor(sv, off);
    if (lane == 0) sg[g] = 1.f / (1.f + expf(-(sv + b_sp[0])));

    float pk = (lane < GFD) ? pocket[(size_t)g * GFD + lane] : 0.f;
    float pgv = b_fc1[lane];
    #pragma unroll 8
    for (int kk = 0; kk < 64; ++kk)
        pgv = fmaf(__shfl(gcv, kk), W_fc1[(64 + kk) * 64 + lane], pgv);
    #pragma unroll 8
    for (int kk = 0; kk < 32; ++kk)
        pgv = fmaf(__shfl(pk, kk), W_fc1[(128 + kk) * 64 + lane], pgv);
    pg[(size_t)g * 64 + lane] = pgv;
}

// ---------------- K4: MFMA head ----------------
__global__ __launch_bounds__(256, 4) void k4_mfma(
    const float* __restrict__ hn, const int* __restrict__ batch,
    const float* __restrict__ pg, const float* __restrict__ sg,
    const unsigned short* __restrict__ W1aT, const unsigned short* __restrict__ W_npT,
    const float* __restrict__ b_np,
    float* __restrict__ out_np, float* __restrict__ out_stop)
{
    __shared__ __align__(16) float sF[4][32][FPAD];
    __shared__ int sB[128];

    const int t = threadIdx.x;
    const int wv = t >> 6, lane = t & 63;
    const int mr = lane & 31, half = lane >> 5;
    const int nb = blockIdx.x * 128;

    if (t < 128) {
        int n = nb + t;
        sB[t] = (n < NN) ? batch[n] : 0;
    }

    const int node = nb + wv * 32 + mr;

    f32x16 acc0, acc1;
    #pragma unroll
    for (int r = 0; r < 16; ++r) { acc0[r] = 0.f; acc1[r] = 0.f; }

    #pragma unroll
    for (int c = 0; c < 4; ++c) {
        short8v a;
        if (node < NN) {
            const float4* hp = (const float4*)(hn + (size_t)node * 64 + c * 16 + half * 8);
            float4 u0 = hp[0], u1 = hp[1];
            union { short8v v; unsigned u[4]; } A;
            A.u[0] = cvtpk(u0.x, u0.y); A.u[1] = cvtpk(u0.z, u0.w);
            A.u[2] = cvtpk(u1.x, u1.y); A.u[3] = cvtpk(u1.z, u1.w);
            a = A.v;
        } else {
            #pragma unroll
            for (int q = 0; q < 8; ++q) a[q] = 0;
        }
        short8v b0 = *(const short8v*)(W1aT + (size_t)mr * 64        + c * 16 + half * 8);
        short8v b1 = *(const short8v*)(W1aT + (size_t)(mr + 32) * 64 + c * 16 + half * 8);
        acc0 = __builtin_amdgcn_mfma_f32_32x32x16_bf16(a, b0, acc0, 0, 0, 0);
        acc1 = __builtin_amdgcn_mfma_f32_32x32x16_bf16(a, b1, acc1, 0, 0, 0);
    }
    __syncthreads();

    #pragma unroll
    for (int r = 0; r < 16; ++r) {
        int row = (r & 3) + 8 * (r >> 2) + 4 * half;
        int g = sB[wv * 32 + row];
        float p0 = pg[(size_t)g * 64 + mr];
        float p1 = pg[(size_t)g * 64 + 32 + mr];
        sF[wv][row][mr]      = fmaxf(acc0[r] + p0, 0.f);
        sF[wv][row][32 + mr] = fmaxf(acc1[r] + p1, 0.f);
    }

    f32x16 acc2, acc3;
    #pragma unroll
    for (int r = 0; r < 16; ++r) { acc2[r] = 0.f; acc3[r] = 0.f; }

    #pragma unroll
    for (int c = 0; c < 4; ++c) {
        const float* fp = &sF[wv][mr][c * 16 + half * 8];
        float4 u0 = *(const float4*)(fp);
        float4 u1 = *(const float4*)(fp + 4);
        union { short8v v; unsigned u[4]; } A;
        A.u[0] = cvtpk(u0.x, u0.y); A.u[1] = cvtpk(u0.z, u0.w);
        A.u[2] = cvtpk(u1.x, u1.y); A.u[3] = cvtpk(u1.z, u1.w);
        short8v a = A.v;
        short8v b0 = *(const short8v*)(W_npT + (size_t)mr * 64        + c * 16 + half * 8);
        short8v b1 = *(const short8v*)(W_npT + (size_t)(mr + 32) * 64 + c * 16 + half * 8);
        acc2 = __builtin_amdgcn_mfma_f32_32x32x16_bf16(a, b0, acc2, 0, 0, 0);
        acc3 = __builtin_amdgcn_mfma_f32_32x32x16_bf16(a, b1, acc3, 0, 0, 0);
    }

    float bn1 = b_np[mr];
    float bn2 = (mr < 8) ? b_np[32 + mr] : 0.f;

    #pragma unroll
    for (int r = 0; r < 16; ++r) {
        int row = (r & 3) + 8 * (r >> 2) + 4 * half;
        int n = nb + wv * 32 + row;
        float v1 = acc2[r] + bn1;
        float v2 = acc3[r] + bn2;
        float m = (mr < 8) ? fmaxf(v1, v2) : v1;
        #pragma unroll
        for (int off = 16; off; off >>= 1) m = fmaxf(m, __shfl_xor(m, off));
        float s = expf(v1 - m) + ((mr < 8) ? expf(v2 - m) : 0.f);
        #pragma unroll
        for (int off = 16; off; off >>= 1) s += __shfl_xor(s, off);
        float ls = m + logf(s);
        if (n < NN) {
            out_np[(size_t)n * CC + mr] = v1 - ls;
            if (mr < 8) out_np[(size_t)n * CC + 32 + mr] = v2 - ls;
            if (mr == 0) out_stop[n] = sg[sB[wv * 32 + row]];
        }
    }
}

extern "C" void kernel_launch(void* const* d_in, const int* in_sizes, int n_in,
                              void* d_out, int out_size, void* d_ws, size_t ws_size,
                              hipStream_t stream)
{
    (void)in_sizes; (void)n_in; (void)out_size;
    const float* x        = (const float*)d_in[0];
    const int*   ei       = (const int*)d_in[1];
    const float* ea       = (const float*)d_in[2];
    const int*   batch    = (const int*)d_in[3];
    const float* pocket   = (const float*)d_in[4];
    const float* W_e1     = (const float*)d_in[5];
    const float* b_e1     = (const float*)d_in[6];
    const float* W_e2     = (const float*)d_in[7];
    const float* b_e2     = (const float*)d_in[8];
    const float* root     = (const float*)d_in[9];
    const float* conv_b   = (const float*)d_in[10];
    const float* Wg       = (const float*)d_in[11];
    const float* bg       = (const float*)d_in[12];
    const float* W_fc1    = (const float*)d_in[13];
    const float* b_fc1    = (const float*)d_in[14];
    const float* W_np     = (const float*)d_in[15];
    const float* b_np     = (const float*)d_in[16];
    const float* W_sp     = (const float*)d_in[17];
    const float* b_sp     = (const float*)d_in[18];

    char* wsb = (char*)d_ws;
    float* agg    = (float*)wsb;                         // NN*64
    int*   cnti   = (int*)(agg + (size_t)NN * 64);       // NN
    int*   base   = cnti + NN;                           // NN+4
    int*   bsum   = base + NN + 4;                       // 256
    int*   cursor = bsum + 256;                          // NN
    int*   rank   = cursor + NN;                         // EE
    float* gate   = (float*)(rank + EE);                 // NN
    float* pg     = gate + NN;                           // GG*64
    float* sg     = pg + (size_t)GG * 64;                // GG
    unsigned short* W2T   = (unsigned short*)(sg + GG);  // 64*W2ROW
    unsigned short* W1aT  = W2T + (size_t)64 * W2ROW;    // 4096
    unsigned short* W_npT = W1aT + 4096;                 // 4096
    size_t head = (size_t)((char*)(W_npT + 4096) - wsb);
    size_t msg_off = (head + 255) & ~(size_t)255;
    unsigned* msg16 = (unsigned*)(wsb + msg_off);        // EE*32 u32
    size_t need = msg_off + (size_t)EE * 32 * sizeof(unsigned);
    const bool twophase = (ws_size >= need);

    hipMemsetAsync(cnti, 0, (size_t)NN * sizeof(int), stream);

    k0_prep<<<(64 * W2ROW + 8192 + 255) / 256, 256, 0, stream>>>(
        W_e2, b_e2, W_fc1, W_np, W2T, W1aT, W_npT);

    kA_hist<<<(EE + 255) / 256, 256, 0, stream>>>(ei, cnti);

    if (twophase) {
        kB_scan1<<<NBLK, 256, 0, stream>>>(cnti, base, bsum);
        kC_scan2<<<1, 256, 0, stream>>>(bsum);
        kD_scan3<<<(NN + 255) / 256, 256, 0, stream>>>(base, bsum, cursor);
        kE_rank<<<(EE + 255) / 256, 256, 0, stream>>>(ei, cursor, rank);

        k1_mfma<true><<<(EE + 255) / 256, 256, 0, stream>>>(
            x, ei, ea, W_e1, b_e1, W2T, rank, msg16, agg);
        k2_red<<<NN / 4, 256, 0, stream>>>(msg16, base, x, root, conv_b,
                                           agg, Wg, bg, gate);
    } else {
        hipMemsetAsync(agg, 0, (size_t)NN * 64 * sizeof(float), stream);
        k1_mfma<false><<<(EE + 255) / 256, 256, 0, stream>>>(
            x, ei, ea, W_e1, b_e1, W2T, rank, msg16, agg);
        k2_node<<<NN / 4, 256, 0, stream>>>(x, root, conv_b, cnti, agg, Wg, bg, gate);
    }

    k3_pool<<<GG, 64, 0, stream>>>(gate, batch, agg, pocket, W_fc1, b_fc1, W_sp, b_sp, pg, sg);

    float* out_np   = (float*)d_out;
    float* out_stop = out_np + (size_t)NN * CC;
    k4_mfma<<<(NN + 127) / 128, 256, 0, stream>>>(agg, batch, pg, sg, W1aT, W_npT, b_np,
                                                  out_np, out_stop);
}

// Round 9
// 341.612 us; speedup vs baseline: 1.1365x; 1.1365x over previous
//
#include <hip/hip_runtime.h>
#include <hip/hip_bf16.h>
#include <math.h>

#define NN 150000
#define EE 600000
#define GG 5000
#define NI 16
#define EI 8
#define GFD 32
#define HH 64
#define CC 40

#define W2ROW 1056
#define FPAD 68
#define NBLK ((NN + 1023) / 1024)

typedef __attribute__((ext_vector_type(8))) short short8v;
typedef __attribute__((ext_vector_type(16))) float f32x16;

__device__ __forceinline__ unsigned short f2bf(float f) {
    __hip_bfloat16 h = __float2bfloat16(f);
    return __builtin_bit_cast(unsigned short, h);
}
__device__ __forceinline__ float bf2f(unsigned short u) {
    return __uint_as_float(((unsigned)u) << 16);
}
__device__ __forceinline__ unsigned cvtpk(float lo, float hi) {
    unsigned r;
    asm("v_cvt_pk_bf16_f32 %0, %1, %2" : "=v"(r) : "v"(lo), "v"(hi));
    return r;
}
__device__ __forceinline__ short8v zfrag(float eh, const float (&xs)[8]) {
    union { short8v v; unsigned u[4]; } A;
    #pragma unroll
    for (int q = 0; q < 4; ++q)
        A.u[q] = cvtpk(eh * xs[2 * q], eh * xs[2 * q + 1]);
    return A.v;
}

// ---------------- K0: prep bf16 weight views ----------------
__global__ void k0_prep(const float* __restrict__ W_e2, const float* __restrict__ b_e2,
                        const float* __restrict__ W_fc1, const float* __restrict__ W_np,
                        unsigned short* __restrict__ W2T,
                        unsigned short* __restrict__ W1aT,
                        unsigned short* __restrict__ W_npT)
{
    int idx = blockIdx.x * 256 + threadIdx.x;
    if (idx < 64 * W2ROW) {
        int h = idx / W2ROW, j = idx % W2ROW;
        float v = 0.f;
        if (j < 1024)      { int k = j >> 4, i = j & 15; v = W_e2[k * 1024 + i * 64 + h]; }
        else if (j < 1040) { int i = j - 1024;           v = b_e2[i * 64 + h]; }
        W2T[idx] = f2bf(v);
    } else if (idx < 64 * W2ROW + 4096) {
        int i = idx - 64 * W2ROW;
        int h = i >> 6, k = i & 63;
        W1aT[i] = f2bf(W_fc1[k * 64 + h]);
    } else if (idx < 64 * W2ROW + 8192) {
        int i = idx - 64 * W2ROW - 4096;
        int c = i >> 6, h = i & 63;
        W_npT[i] = f2bf(c < CC ? W_np[h * CC + c] : 0.f);
    }
}

// ---------------- counting sort (rank only) ----------------
__global__ void kA_hist(const int* __restrict__ ei, int* __restrict__ cnt)
{
    int e = blockIdx.x * 256 + threadIdx.x;
    if (e < EE) atomicAdd(&cnt[ei[EE + e]], 1);
}

__global__ void kB_scan1(const int* __restrict__ cnt, int* __restrict__ base,
                         int* __restrict__ bsum)
{
    __shared__ int sS[256];
    int b = blockIdx.x, t = threadIdx.x;
    int i0 = b * 1024 + t * 4;
    int v0 = (i0 + 0 < NN) ? cnt[i0 + 0] : 0;
    int v1 = (i0 + 1 < NN) ? cnt[i0 + 1] : 0;
    int v2 = (i0 + 2 < NN) ? cnt[i0 + 2] : 0;
    int v3 = (i0 + 3 < NN) ? cnt[i0 + 3] : 0;
    int tot = v0 + v1 + v2 + v3;
    sS[t] = tot;
    __syncthreads();
    int acc = tot;
    for (int off = 1; off < 256; off <<= 1) {
        int xv = (t >= off) ? sS[t - off] : 0;
        __syncthreads();
        acc += xv;
        sS[t] = acc;
        __syncthreads();
    }
    int run = acc - tot;
    if (i0 + 0 < NN) base[i0 + 0] = run; run += v0;
    if (i0 + 1 < NN) base[i0 + 1] = run; run += v1;
    if (i0 + 2 < NN) base[i0 + 2] = run; run += v2;
    if (i0 + 3 < NN) base[i0 + 3] = run;
    if (t == 255) bsum[b] = acc;
}

__global__ void kC_scan2(int* __restrict__ bsum)
{
    __shared__ int sS[256];
    int t = threadIdx.x;
    int v = (t < NBLK) ? bsum[t] : 0;
    sS[t] = v;
    __syncthreads();
    int acc = v;
    for (int off = 1; off < 256; off <<= 1) {
        int xv = (t >= off) ? sS[t - off] : 0;
        __syncthreads();
        acc += xv;
        sS[t] = acc;
        __syncthreads();
    }
    if (t < NBLK) bsum[t] = acc - v;   // exclusive
}

__global__ void kD_scan3(int* __restrict__ base, const int* __restrict__ bsum,
                         int* __restrict__ cursor)
{
    int i = blockIdx.x * 256 + threadIdx.x;
    if (i < NN) {
        int v = base[i] + bsum[i >> 10];
        base[i] = v;
        cursor[i] = v;
    }
    if (i == 0) base[NN] = EE;
}

__global__ void kE_rank(const int* __restrict__ ei, int* __restrict__ cursor,
                        int* __restrict__ rank)
{
    int e = blockIdx.x * 256 + threadIdx.x;
    if (e < EE) {
        int d = ei[EE + e];
        rank[e] = atomicAdd(&cursor[d], 1);
    }
}

// ---------------- shared MFMA inner step ----------------
__device__ __forceinline__ void mfma_step(
    const unsigned short (&sEHT)[65][256], int c, int pf,
    const unsigned short* __restrict__ Bq0, const unsigned short* __restrict__ Bq1,
    int mb, int mr, const float (&xs0)[8], const float (&xs1)[8],
    short8v& curb0, short8v& curb1,
    f32x16& acc00, f32x16& acc01, f32x16& acc10, f32x16& acc11)
{
    short8v n0 = *(const short8v*)(Bq0 + pf * 16);
    short8v n1 = *(const short8v*)(Bq1 + pf * 16);
    int cc = (c & 31) << 1;
    float eh0 = bf2f(sEHT[c][(mb + mr) ^ cc]);
    float eh1 = bf2f(sEHT[c][(mb + 32 + mr) ^ cc]);
    short8v a0 = zfrag(eh0, xs0);
    short8v a1 = zfrag(eh1, xs1);
    __builtin_amdgcn_s_setprio(1);
    acc00 = __builtin_amdgcn_mfma_f32_32x32x16_bf16(a0, curb0, acc00, 0, 0, 0);
    acc01 = __builtin_amdgcn_mfma_f32_32x32x16_bf16(a0, curb1, acc01, 0, 0, 0);
    acc10 = __builtin_amdgcn_mfma_f32_32x32x16_bf16(a1, curb0, acc10, 0, 0, 0);
    acc11 = __builtin_amdgcn_mfma_f32_32x32x16_bf16(a1, curb1, acc11, 0, 0, 0);
    __builtin_amdgcn_s_setprio(0);
    curb0 = n0; curb1 = n1;
}

// ---------------- K1: edge MLP + MFMA z-GEMM; TWOPHASE: bf16 paired store, else atomic ----------------
template<bool TWOPHASE>
__global__ __launch_bounds__(256, 4) void k1_mfma(
    const float* __restrict__ x, const int* __restrict__ ei,
    const float* __restrict__ ea,
    const float* __restrict__ W_e1, const float* __restrict__ b_e1,
    const unsigned short* __restrict__ W2T,
    const int* __restrict__ rank,
    unsigned* __restrict__ msg16, float* __restrict__ agg)
{
    __shared__ unsigned short sEHT[65][256];
    __shared__ int sIdx[256];

    const int t = threadIdx.x;
    const long long eb = (long long)blockIdx.x * 256;

    {
        long long ge = eb + t;
        sIdx[t] = (ge < EE) ? (TWOPHASE ? rank[ge] : ei[EE + ge]) : -1;
        sEHT[64][t] = (unsigned short)0x3F80;   // bias row eh = 1.0
    }
    {
        const int k = t & 63;
        const int w = t >> 6;
        float w1[8];
        float b1 = b_e1[k];
        #pragma unroll
        for (int j = 0; j < 8; ++j) w1[j] = W_e1[j * 64 + k];
        #pragma unroll 4
        for (int r = 0; r < 64; ++r) {
            int e = w * 64 + r;
            long long ge = eb + e;
            float v = 0.f;
            if (ge < EE) {
                const float4* eap = (const float4*)(ea + ge * EI);
                float4 u0 = eap[0], u1 = eap[1];
                v = b1;
                v = fmaf(u0.x, w1[0], v); v = fmaf(u0.y, w1[1], v);
                v = fmaf(u0.z, w1[2], v); v = fmaf(u0.w, w1[3], v);
                v = fmaf(u1.x, w1[4], v); v = fmaf(u1.y, w1[5], v);
                v = fmaf(u1.z, w1[6], v); v = fmaf(u1.w, w1[7], v);
                v = fmaxf(v, 0.f);
            }
            sEHT[k][e ^ ((k & 31) << 1)] = f2bf(v);
        }
    }

    const int lane = t & 63;
    const int w = t >> 6;
    const int mr = lane & 31;
    const int half = lane >> 5;
    const int mb = w * 64;

    float xs0[8], xs1[8];
    {
        long long e0 = eb + mb + mr;
        long long e1 = eb + mb + 32 + mr;
        if (e0 < EE) {
            int s0 = ei[e0];
            const float4* xp = (const float4*)(x + (size_t)s0 * NI + half * 8);
            float4 u0 = xp[0], u1 = xp[1];
            xs0[0]=u0.x; xs0[1]=u0.y; xs0[2]=u0.z; xs0[3]=u0.w;
            xs0[4]=u1.x; xs0[5]=u1.y; xs0[6]=u1.z; xs0[7]=u1.w;
        } else {
            #pragma unroll
            for (int q = 0; q < 8; ++q) xs0[q] = 0.f;
        }
        if (e1 < EE) {
            int s1 = ei[e1];
            const float4* xp = (const float4*)(x + (size_t)s1 * NI + half * 8);
            float4 u0 = xp[0], u1 = xp[1];
            xs1[0]=u0.x; xs1[1]=u0.y; xs1[2]=u0.z; xs1[3]=u0.w;
            xs1[4]=u1.x; xs1[5]=u1.y; xs1[6]=u1.z; xs1[7]=u1.w;
        } else {
            #pragma unroll
            for (int q = 0; q < 8; ++q) xs1[q] = 0.f;
        }
    }
    __syncthreads();

    f32x16 acc00, acc01, acc10, acc11;
    #pragma unroll
    for (int r = 0; r < 16; ++r) { acc00[r] = 0.f; acc01[r] = 0.f; acc10[r] = 0.f; acc11[r] = 0.f; }

    const unsigned short* Bq0 = W2T + (size_t)mr * W2ROW + half * 8;
    const unsigned short* Bq1 = Bq0 + 32 * W2ROW;

    short8v bA0 = *(const short8v*)(Bq0);
    short8v bA1 = *(const short8v*)(Bq1);
    short8v bB0 = *(const short8v*)(Bq0 + 16);
    short8v bB1 = *(const short8v*)(Bq1 + 16);

    #pragma unroll 2
    for (int c = 0; c < 64; c += 2) {
        mfma_step(sEHT, c,     c + 2, Bq0, Bq1, mb, mr, xs0, xs1, bA0, bA1, acc00, acc01, acc10, acc11);
        mfma_step(sEHT, c + 1, c + 3, Bq0, Bq1, mb, mr, xs0, xs1, bB0, bB1, acc00, acc01, acc10, acc11);
    }
    mfma_step(sEHT, 64, 64, Bq0, Bq1, mb, mr, xs0, xs1, bA0, bA1, acc00, acc01, acc10, acc11);

    #pragma unroll
    for (int r = 0; r < 16; ++r) {
        int row = (r & 3) + 8 * (r >> 2) + 4 * half;
        int i0 = sIdx[mb + row];
        int i1 = sIdx[mb + 32 + row];
        if (TWOPHASE) {
            if (i0 >= 0) msg16[(size_t)i0 * 32 + mr] = cvtpk(acc00[r], acc01[r]);
            if (i1 >= 0) msg16[(size_t)i1 * 32 + mr] = cvtpk(acc10[r], acc11[r]);
        } else {
            if (i0 >= 0) {
                atomicAdd(&agg[(size_t)i0 * 64 + mr],      acc00[r]);
                atomicAdd(&agg[(size_t)i0 * 64 + 32 + mr], acc01[r]);
            }
            if (i1 >= 0) {
                atomicAdd(&agg[(size_t)i1 * 64 + mr],      acc10[r]);
                atomicAdd(&agg[(size_t)i1 * 64 + 32 + mr], acc11[r]);
            }
        }
    }
}

// ---------------- K2 (two-phase): stream-reduce bf16 msg16 + mean + root + relu + gate ----------------
__global__ __launch_bounds__(256) void k2_red(
    const unsigned* __restrict__ msg16, const int* __restrict__ base,
    const float* __restrict__ x, const float* __restrict__ root,
    const float* __restrict__ conv_bias,
    unsigned short* __restrict__ hn16,
    const float* __restrict__ Wg, const float* __restrict__ bg,
    float* __restrict__ gate)
{
    __shared__ float sroot[16][64];
    int t = threadIdx.x;
    #pragma unroll
    for (int q = 0; q < 4; ++q) {
        int i = q * 256 + t;
        sroot[i >> 6][i & 63] = root[i];
    }
    __syncthreads();

    int n = blockIdx.x * 4 + (t >> 6);
    int l = t & 63;
    int mr = l & 31, so = l >> 5;
    int s = base[n], e = base[n + 1];

    float alo = 0.f, ahi = 0.f;
    for (int sl = s + so; sl < e; sl += 2) {
        unsigned u = msg16[(size_t)sl * 32 + mr];
        alo += __uint_as_float(u << 16);
        ahi += __uint_as_float(u & 0xFFFF0000u);
    }
    alo += __shfl_xor(alo, 32);
    ahi += __shfl_xor(ahi, 32);
    float acc = (l < 32) ? alo : ahi;

    float inv = 1.0f / fmaxf((float)(e - s), 1.0f);
    float v = acc * inv + conv_bias[l];
    float xv = (l < 16) ? x[(size_t)n * NI + l] : 0.f;
    #pragma unroll
    for (int i = 0; i < 16; ++i)
        v = fmaf(__shfl(xv, i), sroot[i][l], v);
    v = fmaxf(v, 0.f);
    hn16[(size_t)n * 64 + l] = f2bf(v);

    float gv = v * Wg[l];
    #pragma unroll
    for (int off = 32; off; off >>= 1) gv += __shfl_xor(gv, off);
    if (l == 0) gate[n] = gv + bg[0];
}

// ---------------- K2 (fallback): mean + root + relu over agg ----------------
__global__ __launch_bounds__(256) void k2_node(
    const float* __restrict__ agg,
    const float* __restrict__ x, const float* __restrict__ root,
    const float* __restrict__ conv_bias, const int* __restrict__ cnt,
    unsigned short* __restrict__ hn16,
    const float* __restrict__ Wg, const float* __restrict__ bg,
    float* __restrict__ gate)
{
    int t = threadIdx.x;
    int n = blockIdx.x * 4 + (t >> 6);
    int h = t & 63;
    float inv = 1.0f / fmaxf((float)cnt[n], 1.0f);
    float v = agg[(size_t)n * 64 + h] * inv + conv_bias[h];
    const float* xp = x + (size_t)n * NI;
    #pragma unroll
    for (int i = 0; i < NI; ++i) v += xp[i] * root[i * 64 + h];
    v = fmaxf(v, 0.f);
    hn16[(size_t)n * 64 + h] = f2bf(v);
    float gv = v * Wg[h];
    #pragma unroll
    for (int off = 32; off; off >>= 1) gv += __shfl_xor(gv, off);
    if (h == 0) gate[n] = gv + bg[0];
}

// ---------------- K3: per-graph pooling + pg/sg precompute ----------------
__device__ __forceinline__ int lbound(const int* __restrict__ b, int v) {
    int lo = 0, hi = NN;
    while (lo < hi) { int mid = (lo + hi) >> 1; if (b[mid] < v) lo = mid + 1; else hi = mid; }
    return lo;
}

__global__ __launch_bounds__(64) void k3_pool(
    const float* __restrict__ gate, const int* __restrict__ batch,
    const unsigned short* __restrict__ hn16, const float* __restrict__ pocket,
    const float* __restrict__ W_fc1, const float* __restrict__ b_fc1,
    const float* __restrict__ W_sp, const float* __restrict__ b_sp,
    float* __restrict__ pg, float* __restrict__ sg)
{
    int g = blockIdx.x;
    int lane = threadIdx.x;
    int s = lbound(batch, g);
    int e = lbound(batch, g + 1);

    float gcv = 0.f;
    if (e > s) {
        float m = -INFINITY;
        for (int n = s + lane; n < e; n += 64) m = fmaxf(m, gate[n]);
        #pragma unroll
        for (int off = 32; off; off >>= 1) m = fmaxf(m, __shfl_xor(m, off));
        float acc = 0.f, den = 0.f;
        for (int n = s; n < e; ++n) {
            float ev = expf(gate[n] - m);
            den += ev;
            acc += ev * bf2f(hn16[(size_t)n * 64 + lane]);
        }
        gcv = acc / den;
    }

    float sv = gcv * W_sp[lane];
    #pragma unroll
    for (int off = 32; off; off >>= 1) sv += __shfl_xor(sv, off);
    if (lane == 0) sg[g] = 1.f / (1.f + expf(-(sv + b_sp[0])));

    float pk = (lane < GFD) ? pocket[(size_t)g * GFD + lane] : 0.f;
    float pgv = b_fc1[lane];
    #pragma unroll 8
    for (int kk = 0; kk < 64; ++kk)
        pgv = fmaf(__shfl(gcv, kk), W_fc1[(64 + kk) * 64 + lane], pgv);
    #pragma unroll 8
    for (int kk = 0; kk < 32; ++kk)
        pgv = fmaf(__shfl(pk, kk), W_fc1[(128 + kk) * 64 + lane], pgv);
    pg[(size_t)g * 64 + lane] = pgv;
}

// ---------------- K4: MFMA head ----------------
__global__ __launch_bounds__(256, 4) void k4_mfma(
    const unsigned short* __restrict__ hn16, const int* __restrict__ batch,
    const float* __restrict__ pg, const float* __restrict__ sg,
    const unsigned short* __restrict__ W1aT, const unsigned short* __restrict__ W_npT,
    const float* __restrict__ b_np,
    float* __restrict__ out_np, float* __restrict__ out_stop)
{
    __shared__ __align__(16) float sF[4][32][FPAD];
    __shared__ int sB[128];

    const int t = threadIdx.x;
    const int wv = t >> 6, lane = t & 63;
    const int mr = lane & 31, half = lane >> 5;
    const int nb = blockIdx.x * 128;

    if (t < 128) {
        int n = nb + t;
        sB[t] = (n < NN) ? batch[n] : 0;
    }

    const int node = nb + wv * 32 + mr;

    f32x16 acc0, acc1;
    #pragma unroll
    for (int r = 0; r < 16; ++r) { acc0[r] = 0.f; acc1[r] = 0.f; }

    #pragma unroll
    for (int c = 0; c < 4; ++c) {
        short8v a;
        if (node < NN) {
            a = *(const short8v*)(hn16 + (size_t)node * 64 + c * 16 + half * 8);
        } else {
            #pragma unroll
            for (int q = 0; q < 8; ++q) a[q] = 0;
        }
        short8v b0 = *(const short8v*)(W1aT + (size_t)mr * 64        + c * 16 + half * 8);
        short8v b1 = *(const short8v*)(W1aT + (size_t)(mr + 32) * 64 + c * 16 + half * 8);
        acc0 = __builtin_amdgcn_mfma_f32_32x32x16_bf16(a, b0, acc0, 0, 0, 0);
        acc1 = __builtin_amdgcn_mfma_f32_32x32x16_bf16(a, b1, acc1, 0, 0, 0);
    }
    __syncthreads();

    #pragma unroll
    for (int r = 0; r < 16; ++r) {
        int row = (r & 3) + 8 * (r >> 2) + 4 * half;
        int g = sB[wv * 32 + row];
        float p0 = pg[(size_t)g * 64 + mr];
        float p1 = pg[(size_t)g * 64 + 32 + mr];
        sF[wv][row][mr]      = fmaxf(acc0[r] + p0, 0.f);
        sF[wv][row][32 + mr] = fmaxf(acc1[r] + p1, 0.f);
    }

    f32x16 acc2, acc3;
    #pragma unroll
    for (int r = 0; r < 16; ++r) { acc2[r] = 0.f; acc3[r] = 0.f; }

    #pragma unroll
    for (int c = 0; c < 4; ++c) {
        const float* fp = &sF[wv][mr][c * 16 + half * 8];
        float4 u0 = *(const float4*)(fp);
        float4 u1 = *(const float4*)(fp + 4);
        union { short8v v; unsigned u[4]; } A;
        A.u[0] = cvtpk(u0.x, u0.y); A.u[1] = cvtpk(u0.z, u0.w);
        A.u[2] = cvtpk(u1.x, u1.y); A.u[3] = cvtpk(u1.z, u1.w);
        short8v a = A.v;
        short8v b0 = *(const short8v*)(W_npT + (size_t)mr * 64        + c * 16 + half * 8);
        short8v b1 = *(const short8v*)(W_npT + (size_t)(mr + 32) * 64 + c * 16 + half * 8);
        acc2 = __builtin_amdgcn_mfma_f32_32x32x16_bf16(a, b0, acc2, 0, 0, 0);
        acc3 = __builtin_amdgcn_mfma_f32_32x32x16_bf16(a, b1, acc3, 0, 0, 0);
    }

    float bn1 = b_np[mr];
    float bn2 = (mr < 8) ? b_np[32 + mr] : 0.f;

    #pragma unroll
    for (int r = 0; r < 16; ++r) {
        int row = (r & 3) + 8 * (r >> 2) + 4 * half;
        int n = nb + wv * 32 + row;
        float v1 = acc2[r] + bn1;
        float v2 = acc3[r] + bn2;
        float m = (mr < 8) ? fmaxf(v1, v2) : v1;
        #pragma unroll
        for (int off = 16; off; off >>= 1) m = fmaxf(m, __shfl_xor(m, off));
        float s = expf(v1 - m) + ((mr < 8) ? expf(v2 - m) : 0.f);
        #pragma unroll
        for (int off = 16; off; off >>= 1) s += __shfl_xor(s, off);
        float ls = m + logf(s);
        if (n < NN) {
            out_np[(size_t)n * CC + mr] = v1 - ls;
            if (mr < 8) out_np[(size_t)n * CC + 32 + mr] = v2 - ls;
            if (mr == 0) out_stop[n] = sg[sB[wv * 32 + row]];
        }
    }
}

extern "C" void kernel_launch(void* const* d_in, const int* in_sizes, int n_in,
                              void* d_out, int out_size, void* d_ws, size_t ws_size,
                              hipStream_t stream)
{
    (void)in_sizes; (void)n_in; (void)out_size;
    const float* x        = (const float*)d_in[0];
    const int*   ei       = (const int*)d_in[1];
    const float* ea       = (const float*)d_in[2];
    const int*   batch    = (const int*)d_in[3];
    const float* pocket   = (const float*)d_in[4];
    const float* W_e1     = (const float*)d_in[5];
    const float* b_e1     = (const float*)d_in[6];
    const float* W_e2     = (const float*)d_in[7];
    const float* b_e2     = (const float*)d_in[8];
    const float* root     = (const float*)d_in[9];
    const float* conv_b   = (const float*)d_in[10];
    const float* Wg       = (const float*)d_in[11];
    const float* bg       = (const float*)d_in[12];
    const float* W_fc1    = (const float*)d_in[13];
    const float* b_fc1    = (const float*)d_in[14];
    const float* W_np     = (const float*)d_in[15];
    const float* b_np     = (const float*)d_in[16];
    const float* W_sp     = (const float*)d_in[17];
    const float* b_sp     = (const float*)d_in[18];

    char* wsb = (char*)d_ws;
    float* agg    = (float*)wsb;                         // NN*64 (atomic fallback)
    int*   cnti   = (int*)(agg + (size_t)NN * 64);       // NN
    int*   base   = cnti + NN;                           // NN+4
    int*   bsum   = base + NN + 4;                       // 256
    int*   cursor = bsum + 256;                          // NN
    int*   rank   = cursor + NN;                         // EE
    float* gate   = (float*)(rank + EE);                 // NN
    float* pg     = gate + NN;                           // GG*64
    float* sg     = pg + (size_t)GG * 64;                // GG
    unsigned short* hn16  = (unsigned short*)(sg + GG);  // NN*64 u16
    unsigned short* W2T   = hn16 + (size_t)NN * 64;      // 64*W2ROW
    unsigned short* W1aT  = W2T + (size_t)64 * W2ROW;    // 4096
    unsigned short* W_npT = W1aT + 4096;                 // 4096
    size_t head = (size_t)((char*)(W_npT + 4096) - wsb);
    size_t msg_off = (head + 255) & ~(size_t)255;
    unsigned* msg16 = (unsigned*)(wsb + msg_off);        // EE*32 u32
    size_t need = msg_off + (size_t)EE * 32 * sizeof(unsigned);
    const bool twophase = (ws_size >= need);

    hipMemsetAsync(cnti, 0, (size_t)NN * sizeof(int), stream);

    k0_prep<<<(64 * W2ROW + 8192 + 255) / 256, 256, 0, stream>>>(
        W_e2, b_e2, W_fc1, W_np, W2T, W1aT, W_npT);

    kA_hist<<<(EE + 255) / 256, 256, 0, stream>>>(ei, cnti);

    if (twophase) {
        kB_scan1<<<NBLK, 256, 0, stream>>>(cnti, base, bsum);
        kC_scan2<<<1, 256, 0, stream>>>(bsum);
        kD_scan3<<<(NN + 255) / 256, 256, 0, stream>>>(base, bsum, cursor);
        kE_rank<<<(EE + 255) / 256, 256, 0, stream>>>(ei, cursor, rank);

        k1_mfma<true><<<(EE + 255) / 256, 256, 0, stream>>>(
            x, ei, ea, W_e1, b_e1, W2T, rank, msg16, agg);
        k2_red<<<NN / 4, 256, 0, stream>>>(msg16, base, x, root, conv_b,
                                           hn16, Wg, bg, gate);
    } else {
        hipMemsetAsync(agg, 0, (size_t)NN * 64 * sizeof(float), stream);
        k1_mfma<false><<<(EE + 255) / 256, 256, 0, stream>>>(
            x, ei, ea, W_e1, b_e1, W2T, rank, msg16, agg);
        k2_node<<<NN / 4, 256, 0, stream>>>(agg, x, root, conv_b, cnti, hn16, Wg, bg, gate);
    }

    k3_pool<<<GG, 64, 0, stream>>>(gate, batch, hn16, pocket, W_fc1, b_fc1, W_sp, b_sp, pg, sg);

    float* out_np   = (float*)d_out;
    float* out_stop = out_np + (size_t)NN * CC;
    k4_mfma<<<(NN + 127) / 128, 256, 0, stream>>>(hn16, batch, pg, sg, W1aT, W_npT, b_np,
                                                  out_np, out_stop);
}

// Round 10
// 316.436 us; speedup vs baseline: 1.2269x; 1.0796x over previous
//
#include <hip/hip_runtime.h>
#include <hip/hip_bf16.h>
#include <math.h>

#define NN 150000
#define EE 600000
#define GG 5000
#define NI 16
#define EI 8
#define GFD 32
#define HH 64
#define CC 40

#define W2ROW 1056
#define FPAD 68
#define NBLK ((NN + 1023) / 1024)

typedef __attribute__((ext_vector_type(8))) short short8v;
typedef __attribute__((ext_vector_type(16))) float f32x16;
typedef __attribute__((ext_vector_type(2))) float f32x2;

__device__ __forceinline__ unsigned short f2bf(float f) {
    __hip_bfloat16 h = __float2bfloat16(f);
    return __builtin_bit_cast(unsigned short, h);
}
__device__ __forceinline__ float bf2f(unsigned short u) {
    return __uint_as_float(((unsigned)u) << 16);
}
__device__ __forceinline__ unsigned cvtpk(float lo, float hi) {
    unsigned r;
    asm("v_cvt_pk_bf16_f32 %0, %1, %2" : "=v"(r) : "v"(lo), "v"(hi));
    return r;
}
// packed f32 pair multiply (VOP3P) — exact 2x f32 mul in one instruction
__device__ __forceinline__ f32x2 pkmul(f32x2 a, f32x2 b) {
    f32x2 p;
    asm("v_pk_mul_f32 %0, %1, %2" : "=v"(p) : "v"(a), "v"(b));
    return p;
}
__device__ __forceinline__ short8v zfrag(float eh, const f32x2 (&xs2)[4]) {
    f32x2 ehp; ehp[0] = eh; ehp[1] = eh;
    union { short8v v; unsigned u[4]; } A;
    #pragma unroll
    for (int q = 0; q < 4; ++q) {
        f32x2 p = pkmul(ehp, xs2[q]);
        A.u[q] = cvtpk(p[0], p[1]);
    }
    return A.v;
}
__device__ __forceinline__ short8v xfrag(const f32x2 (&xs2)[4]) {
    union { short8v v; unsigned u[4]; } A;
    #pragma unroll
    for (int q = 0; q < 4; ++q)
        A.u[q] = cvtpk(xs2[q][0], xs2[q][1]);
    return A.v;
}

// ---------------- K0: prep bf16 weight views + zero cursor ----------------
__global__ void k0_prep(const float* __restrict__ W_e2, const float* __restrict__ b_e2,
                        const float* __restrict__ W_fc1, const float* __restrict__ W_np,
                        unsigned short* __restrict__ W2T,
                        unsigned short* __restrict__ W1aT,
                        unsigned short* __restrict__ W_npT,
                        int* __restrict__ cursor)
{
    int idx = blockIdx.x * 256 + threadIdx.x;
    if (idx < 64 * W2ROW) {
        int h = idx / W2ROW, j = idx % W2ROW;
        float v = 0.f;
        if (j < 1024)      { int k = j >> 4, i = j & 15; v = W_e2[k * 1024 + i * 64 + h]; }
        else if (j < 1040) { int i = j - 1024;           v = b_e2[i * 64 + h]; }
        W2T[idx] = f2bf(v);
    } else if (idx < 64 * W2ROW + 4096) {
        int i = idx - 64 * W2ROW;
        int h = i >> 6, k = i & 63;
        W1aT[i] = f2bf(W_fc1[k * 64 + h]);
    } else if (idx < 64 * W2ROW + 8192) {
        int i = idx - 64 * W2ROW - 4096;
        int c = i >> 6, h = i & 63;
        W_npT[i] = f2bf(c < CC ? W_np[h * CC + c] : 0.f);
    } else if (idx < 64 * W2ROW + 8192 + NN) {
        cursor[idx - 64 * W2ROW - 8192] = 0;
    }
}

// ---------------- kE_local: local rank within dst + counts (single atomic pass) ----------------
__global__ void kE_local(const int* __restrict__ ei, int* __restrict__ cursor,
                         int* __restrict__ rank)
{
    int e = blockIdx.x * 256 + threadIdx.x;
    if (e < EE) rank[e] = atomicAdd(&cursor[ei[EE + e]], 1);
}

// ---------------- scan of counts -> base ----------------
__global__ void kB_scan1(const int* __restrict__ cnt, int* __restrict__ base,
                         int* __restrict__ bsum)
{
    __shared__ int sS[256];
    int b = blockIdx.x, t = threadIdx.x;
    int i0 = b * 1024 + t * 4;
    int v0 = (i0 + 0 < NN) ? cnt[i0 + 0] : 0;
    int v1 = (i0 + 1 < NN) ? cnt[i0 + 1] : 0;
    int v2 = (i0 + 2 < NN) ? cnt[i0 + 2] : 0;
    int v3 = (i0 + 3 < NN) ? cnt[i0 + 3] : 0;
    int tot = v0 + v1 + v2 + v3;
    sS[t] = tot;
    __syncthreads();
    int acc = tot;
    for (int off = 1; off < 256; off <<= 1) {
        int xv = (t >= off) ? sS[t - off] : 0;
        __syncthreads();
        acc += xv;
        sS[t] = acc;
        __syncthreads();
    }
    int run = acc - tot;
    if (i0 + 0 < NN) base[i0 + 0] = run; run += v0;
    if (i0 + 1 < NN) base[i0 + 1] = run; run += v1;
    if (i0 + 2 < NN) base[i0 + 2] = run; run += v2;
    if (i0 + 3 < NN) base[i0 + 3] = run;
    if (t == 255) bsum[b] = acc;
}

__global__ void kC_scan2(int* __restrict__ bsum)
{
    __shared__ int sS[256];
    int t = threadIdx.x;
    int v = (t < NBLK) ? bsum[t] : 0;
    sS[t] = v;
    __syncthreads();
    int acc = v;
    for (int off = 1; off < 256; off <<= 1) {
        int xv = (t >= off) ? sS[t - off] : 0;
        __syncthreads();
        acc += xv;
        sS[t] = acc;
        __syncthreads();
    }
    if (t < NBLK) bsum[t] = acc - v;   // exclusive
}

__global__ void kD_scan3(int* __restrict__ base, const int* __restrict__ bsum)
{
    int i = blockIdx.x * 256 + threadIdx.x;
    if (i < NN) base[i] = base[i] + bsum[i >> 10];
    if (i == 0) base[NN] = EE;
}

// ---------------- shared MFMA inner step ----------------
__device__ __forceinline__ void mfma_step(
    const unsigned short (&sEHT)[65][256], int c, int pf,
    const unsigned short* __restrict__ Bq0, const unsigned short* __restrict__ Bq1,
    int mb, int mr, const f32x2 (&xs0)[4], const f32x2 (&xs1)[4],
    short8v& curb0, short8v& curb1,
    f32x16& acc00, f32x16& acc01, f32x16& acc10, f32x16& acc11)
{
    short8v n0 = *(const short8v*)(Bq0 + pf * 16);
    short8v n1 = *(const short8v*)(Bq1 + pf * 16);
    int cc = (c & 31) << 1;
    float eh0 = bf2f(sEHT[c][(mb + mr) ^ cc]);
    float eh1 = bf2f(sEHT[c][(mb + 32 + mr) ^ cc]);
    short8v a0 = zfrag(eh0, xs0);
    short8v a1 = zfrag(eh1, xs1);
    __builtin_amdgcn_s_setprio(1);
    acc00 = __builtin_amdgcn_mfma_f32_32x32x16_bf16(a0, curb0, acc00, 0, 0, 0);
    acc01 = __builtin_amdgcn_mfma_f32_32x32x16_bf16(a0, curb1, acc01, 0, 0, 0);
    acc10 = __builtin_amdgcn_mfma_f32_32x32x16_bf16(a1, curb0, acc10, 0, 0, 0);
    acc11 = __builtin_amdgcn_mfma_f32_32x32x16_bf16(a1, curb1, acc11, 0, 0, 0);
    __builtin_amdgcn_s_setprio(0);
    curb0 = n0; curb1 = n1;
}

// ---------------- K1: edge MLP + MFMA z-GEMM; TWOPHASE: bf16 paired store, else atomic ----------------
template<bool TWOPHASE>
__global__ __launch_bounds__(256, 4) void k1_mfma(
    const float* __restrict__ x, const int* __restrict__ ei,
    const float* __restrict__ ea,
    const float* __restrict__ W_e1, const float* __restrict__ b_e1,
    const unsigned short* __restrict__ W2T,
    const int* __restrict__ rank, const int* __restrict__ base,
    unsigned* __restrict__ msg16, float* __restrict__ agg)
{
    __shared__ unsigned short sEHT[65][256];
    __shared__ int sIdx[256];

    const int t = threadIdx.x;
    const long long eb = (long long)blockIdx.x * 256;

    {
        long long ge = eb + t;
        if (ge < EE) {
            int d = ei[EE + ge];
            sIdx[t] = TWOPHASE ? (base[d] + rank[ge]) : d;
        } else {
            sIdx[t] = -1;
        }
        sEHT[64][t] = (unsigned short)0x3F80;   // bias row eh = 1.0
    }
    {
        const int k = t & 63;
        const int w = t >> 6;
        float w1[8];
        float b1 = b_e1[k];
        #pragma unroll
        for (int j = 0; j < 8; ++j) w1[j] = W_e1[j * 64 + k];
        #pragma unroll 4
        for (int r = 0; r < 64; ++r) {
            int e = w * 64 + r;
            long long ge = eb + e;
            float v = 0.f;
            if (ge < EE) {
                const float4* eap = (const float4*)(ea + ge * EI);
                float4 u0 = eap[0], u1 = eap[1];
                v = b1;
                v = fmaf(u0.x, w1[0], v); v = fmaf(u0.y, w1[1], v);
                v = fmaf(u0.z, w1[2], v); v = fmaf(u0.w, w1[3], v);
                v = fmaf(u1.x, w1[4], v); v = fmaf(u1.y, w1[5], v);
                v = fmaf(u1.z, w1[6], v); v = fmaf(u1.w, w1[7], v);
                v = fmaxf(v, 0.f);
            }
            sEHT[k][e ^ ((k & 31) << 1)] = f2bf(v);
        }
    }

    const int lane = t & 63;
    const int w = t >> 6;
    const int mr = lane & 31;
    const int half = lane >> 5;
    const int mb = w * 64;

    f32x2 xs0[4], xs1[4];
    {
        long long e0 = eb + mb + mr;
        long long e1 = eb + mb + 32 + mr;
        if (e0 < EE) {
            int s0 = ei[e0];
            const float4* xp = (const float4*)(x + (size_t)s0 * NI + half * 8);
            float4 u0 = xp[0], u1 = xp[1];
            xs0[0][0]=u0.x; xs0[0][1]=u0.y; xs0[1][0]=u0.z; xs0[1][1]=u0.w;
            xs0[2][0]=u1.x; xs0[2][1]=u1.y; xs0[3][0]=u1.z; xs0[3][1]=u1.w;
        } else {
            #pragma unroll
            for (int q = 0; q < 4; ++q) { xs0[q][0] = 0.f; xs0[q][1] = 0.f; }
        }
        if (e1 < EE) {
            int s1 = ei[e1];
            const float4* xp = (const float4*)(x + (size_t)s1 * NI + half * 8);
            float4 u0 = xp[0], u1 = xp[1];
            xs1[0][0]=u0.x; xs1[0][1]=u0.y; xs1[1][0]=u0.z; xs1[1][1]=u0.w;
            xs1[2][0]=u1.x; xs1[2][1]=u1.y; xs1[3][0]=u1.z; xs1[3][1]=u1.w;
        } else {
            #pragma unroll
            for (int q = 0; q < 4; ++q) { xs1[q][0] = 0.f; xs1[q][1] = 0.f; }
        }
    }
    __syncthreads();

    f32x16 acc00, acc01, acc10, acc11;
    #pragma unroll
    for (int r = 0; r < 16; ++r) { acc00[r] = 0.f; acc01[r] = 0.f; acc10[r] = 0.f; acc11[r] = 0.f; }

    const unsigned short* Bq0 = W2T + (size_t)mr * W2ROW + half * 8;
    const unsigned short* Bq1 = Bq0 + 32 * W2ROW;

    short8v bA0 = *(const short8v*)(Bq0);
    short8v bA1 = *(const short8v*)(Bq1);
    short8v bB0 = *(const short8v*)(Bq0 + 16);
    short8v bB1 = *(const short8v*)(Bq1 + 16);

    #pragma unroll 2
    for (int c = 0; c < 64; c += 2) {
        mfma_step(sEHT, c,     c + 2, Bq0, Bq1, mb, mr, xs0, xs1, bA0, bA1, acc00, acc01, acc10, acc11);
        mfma_step(sEHT, c + 1, c + 3, Bq0, Bq1, mb, mr, xs0, xs1, bB0, bB1, acc00, acc01, acc10, acc11);
    }
    // bias chunk c=64: eh = 1 -> A = bf16(xs); B in bA (prefetched at c=62)
    {
        short8v a0 = xfrag(xs0);
        short8v a1 = xfrag(xs1);
        __builtin_amdgcn_s_setprio(1);
        acc00 = __builtin_amdgcn_mfma_f32_32x32x16_bf16(a0, bA0, acc00, 0, 0, 0);
        acc01 = __builtin_amdgcn_mfma_f32_32x32x16_bf16(a0, bA1, acc01, 0, 0, 0);
        acc10 = __builtin_amdgcn_mfma_f32_32x32x16_bf16(a1, bA0, acc10, 0, 0, 0);
        acc11 = __builtin_amdgcn_mfma_f32_32x32x16_bf16(a1, bA1, acc11, 0, 0, 0);
        __builtin_amdgcn_s_setprio(0);
    }

    #pragma unroll
    for (int r = 0; r < 16; ++r) {
        int row = (r & 3) + 8 * (r >> 2) + 4 * half;
        int i0 = sIdx[mb + row];
        int i1 = sIdx[mb + 32 + row];
        if (TWOPHASE) {
            if (i0 >= 0) msg16[(size_t)i0 * 32 + mr] = cvtpk(acc00[r], acc01[r]);
            if (i1 >= 0) msg16[(size_t)i1 * 32 + mr] = cvtpk(acc10[r], acc11[r]);
        } else {
            if (i0 >= 0) {
                atomicAdd(&agg[(size_t)i0 * 64 + mr],      acc00[r]);
                atomicAdd(&agg[(size_t)i0 * 64 + 32 + mr], acc01[r]);
            }
            if (i1 >= 0) {
                atomicAdd(&agg[(size_t)i1 * 64 + mr],      acc10[r]);
                atomicAdd(&agg[(size_t)i1 * 64 + 32 + mr], acc11[r]);
            }
        }
    }
}

// ---------------- K2 (two-phase): stream-reduce bf16 msg16 + mean + root + relu + gate ----------------
__global__ __launch_bounds__(256) void k2_red(
    const unsigned* __restrict__ msg16, const int* __restrict__ base,
    const float* __restrict__ x, const float* __restrict__ root,
    const float* __restrict__ conv_bias,
    unsigned short* __restrict__ hn16,
    const float* __restrict__ Wg, const float* __restrict__ bg,
    float* __restrict__ gate)
{
    __shared__ float sroot[16][64];
    int t = threadIdx.x;
    #pragma unroll
    for (int q = 0; q < 4; ++q) {
        int i = q * 256 + t;
        sroot[i >> 6][i & 63] = root[i];
    }
    __syncthreads();

    int n = blockIdx.x * 4 + (t >> 6);
    int l = t & 63;
    int mr = l & 31, so = l >> 5;
    int s = base[n], e = base[n + 1];

    float alo = 0.f, ahi = 0.f;
    for (int sl = s + so; sl < e; sl += 2) {
        unsigned u = msg16[(size_t)sl * 32 + mr];
        alo += __uint_as_float(u << 16);
        ahi += __uint_as_float(u & 0xFFFF0000u);
    }
    alo += __shfl_xor(alo, 32);
    ahi += __shfl_xor(ahi, 32);
    float acc = (l < 32) ? alo : ahi;

    float inv = 1.0f / fmaxf((float)(e - s), 1.0f);
    float v = acc * inv + conv_bias[l];
    float xv = (l < 16) ? x[(size_t)n * NI + l] : 0.f;
    #pragma unroll
    for (int i = 0; i < 16; ++i)
        v = fmaf(__shfl(xv, i), sroot[i][l], v);
    v = fmaxf(v, 0.f);
    hn16[(size_t)n * 64 + l] = f2bf(v);

    float gv = v * Wg[l];
    #pragma unroll
    for (int off = 32; off; off >>= 1) gv += __shfl_xor(gv, off);
    if (l == 0) gate[n] = gv + bg[0];
}

// ---------------- K2 (fallback): mean + root + relu over agg ----------------
__global__ __launch_bounds__(256) void k2_node(
    const float* __restrict__ agg, const int* __restrict__ base,
    const float* __restrict__ x, const float* __restrict__ root,
    const float* __restrict__ conv_bias,
    unsigned short* __restrict__ hn16,
    const float* __restrict__ Wg, const float* __restrict__ bg,
    float* __restrict__ gate)
{
    int t = threadIdx.x;
    int n = blockIdx.x * 4 + (t >> 6);
    int h = t & 63;
    float cntv = (float)(base[n + 1] - base[n]);
    float inv = 1.0f / fmaxf(cntv, 1.0f);
    float v = agg[(size_t)n * 64 + h] * inv + conv_bias[h];
    const float* xp = x + (size_t)n * NI;
    #pragma unroll
    for (int i = 0; i < NI; ++i) v += xp[i] * root[i * 64 + h];
    v = fmaxf(v, 0.f);
    hn16[(size_t)n * 64 + h] = f2bf(v);
    float gv = v * Wg[h];
    #pragma unroll
    for (int off = 32; off; off >>= 1) gv += __shfl_xor(gv, off);
    if (h == 0) gate[n] = gv + bg[0];
}

// ---------------- K3: per-graph pooling + pg/sg precompute ----------------
__device__ __forceinline__ int lbound(const int* __restrict__ b, int v) {
    int lo = 0, hi = NN;
    while (lo < hi) { int mid = (lo + hi) >> 1; if (b[mid] < v) lo = mid + 1; else hi = mid; }
    return lo;
}

__global__ __launch_bounds__(64) void k3_pool(
    const float* __restrict__ gate, const int* __restrict__ batch,
    const unsigned short* __restrict__ hn16, const float* __restrict__ pocket,
    const float* __restrict__ W_fc1, const float* __restrict__ b_fc1,
    const float* __restrict__ W_sp, const float* __restrict__ b_sp,
    float* __restrict__ pg, float* __restrict__ sg)
{
    int g = blockIdx.x;
    int lane = threadIdx.x;
    int s = lbound(batch, g);
    int e = lbound(batch, g + 1);

    float gcv = 0.f;
    if (e > s) {
        float m = -INFINITY;
        for (int n = s + lane; n < e; n += 64) m = fmaxf(m, gate[n]);
        #pragma unroll
        for (int off = 32; off; off >>= 1) m = fmaxf(m, __shfl_xor(m, off));
        float acc = 0.f, den = 0.f;
        for (int n = s; n < e; ++n) {
            float ev = expf(gate[n] - m);
            den += ev;
            acc += ev * bf2f(hn16[(size_t)n * 64 + lane]);
        }
        gcv = acc / den;
    }

    float sv = gcv * W_sp[lane];
    #pragma unroll
    for (int off = 32; off; off >>= 1) sv += __shfl_xor(sv, off);
    if (lane == 0) sg[g] = 1.f / (1.f + expf(-(sv + b_sp[0])));

    float pk = (lane < GFD) ? pocket[(size_t)g * GFD + lane] : 0.f;
    float pgv = b_fc1[lane];
    #pragma unroll 8
    for (int kk = 0; kk < 64; ++kk)
        pgv = fmaf(__shfl(gcv, kk), W_fc1[(64 + kk) * 64 + lane], pgv);
    #pragma unroll 8
    for (int kk = 0; kk < 32; ++kk)
        pgv = fmaf(__shfl(pk, kk), W_fc1[(128 + kk) * 64 + lane], pgv);
    pg[(size_t)g * 64 + lane] = pgv;
}

// ---------------- K4: MFMA head ----------------
__global__ __launch_bounds__(256, 4) void k4_mfma(
    const unsigned short* __restrict__ hn16, const int* __restrict__ batch,
    const float* __restrict__ pg, const float* __restrict__ sg,
    const unsigned short* __restrict__ W1aT, const unsigned short* __restrict__ W_npT,
    const float* __restrict__ b_np,
    float* __restrict__ out_np, float* __restrict__ out_stop)
{
    __shared__ __align__(16) float sF[4][32][FPAD];
    __shared__ int sB[128];

    const int t = threadIdx.x;
    const int wv = t >> 6, lane = t & 63;
    const int mr = lane & 31, half = lane >> 5;
    const int nb = blockIdx.x * 128;

    if (t < 128) {
        int n = nb + t;
        sB[t] = (n < NN) ? batch[n] : 0;
    }

    const int node = nb + wv * 32 + mr;

    f32x16 acc0, acc1;
    #pragma unroll
    for (int r = 0; r < 16; ++r) { acc0[r] = 0.f; acc1[r] = 0.f; }

    #pragma unroll
    for (int c = 0; c < 4; ++c) {
        short8v a;
        if (node < NN) {
            a = *(const short8v*)(hn16 + (size_t)node * 64 + c * 16 + half * 8);
        } else {
            #pragma unroll
            for (int q = 0; q < 8; ++q) a[q] = 0;
        }
        short8v b0 = *(const short8v*)(W1aT + (size_t)mr * 64        + c * 16 + half * 8);
        short8v b1 = *(const short8v*)(W1aT + (size_t)(mr + 32) * 64 + c * 16 + half * 8);
        acc0 = __builtin_amdgcn_mfma_f32_32x32x16_bf16(a, b0, acc0, 0, 0, 0);
        acc1 = __builtin_amdgcn_mfma_f32_32x32x16_bf16(a, b1, acc1, 0, 0, 0);
    }
    __syncthreads();

    #pragma unroll
    for (int r = 0; r < 16; ++r) {
        int row = (r & 3) + 8 * (r >> 2) + 4 * half;
        int g = sB[wv * 32 + row];
        float p0 = pg[(size_t)g * 64 + mr];
        float p1 = pg[(size_t)g * 64 + 32 + mr];
        sF[wv][row][mr]      = fmaxf(acc0[r] + p0, 0.f);
        sF[wv][row][32 + mr] = fmaxf(acc1[r] + p1, 0.f);
    }

    f32x16 acc2, acc3;
    #pragma unroll
    for (int r = 0; r < 16; ++r) { acc2[r] = 0.f; acc3[r] = 0.f; }

    #pragma unroll
    for (int c = 0; c < 4; ++c) {
        const float* fp = &sF[wv][mr][c * 16 + half * 8];
        float4 u0 = *(const float4*)(fp);
        float4 u1 = *(const float4*)(fp + 4);
        union { short8v v; unsigned u[4]; } A;
        A.u[0] = cvtpk(u0.x, u0.y); A.u[1] = cvtpk(u0.z, u0.w);
        A.u[2] = cvtpk(u1.x, u1.y); A.u[3] = cvtpk(u1.z, u1.w);
        short8v a = A.v;
        short8v b0 = *(const short8v*)(W_npT + (size_t)mr * 64        + c * 16 + half * 8);
        short8v b1 = *(const short8v*)(W_npT + (size_t)(mr + 32) * 64 + c * 16 + half * 8);
        acc2 = __builtin_amdgcn_mfma_f32_32x32x16_bf16(a, b0, acc2, 0, 0, 0);
        acc3 = __builtin_amdgcn_mfma_f32_32x32x16_bf16(a, b1, acc3, 0, 0, 0);
    }

    float bn1 = b_np[mr];
    float bn2 = (mr < 8) ? b_np[32 + mr] : 0.f;

    #pragma unroll
    for (int r = 0; r < 16; ++r) {
        int row = (r & 3) + 8 * (r >> 2) + 4 * half;
        int n = nb + wv * 32 + row;
        float v1 = acc2[r] + bn1;
        float v2 = acc3[r] + bn2;
        float m = (mr < 8) ? fmaxf(v1, v2) : v1;
        #pragma unroll
        for (int off = 16; off; off >>= 1) m = fmaxf(m, __shfl_xor(m, off));
        float s = expf(v1 - m) + ((mr < 8) ? expf(v2 - m) : 0.f);
        #pragma unroll
        for (int off = 16; off; off >>= 1) s += __shfl_xor(s, off);
        float ls = m + logf(s);
        if (n < NN) {
            out_np[(size_t)n * CC + mr] = v1 - ls;
            if (mr < 8) out_np[(size_t)n * CC + 32 + mr] = v2 - ls;
            if (mr == 0) out_stop[n] = sg[sB[wv * 32 + row]];
        }
    }
}

extern "C" void kernel_launch(void* const* d_in, const int* in_sizes, int n_in,
                              void* d_out, int out_size, void* d_ws, size_t ws_size,
                              hipStream_t stream)
{
    (void)in_sizes; (void)n_in; (void)out_size;
    const float* x        = (const float*)d_in[0];
    const int*   ei       = (const int*)d_in[1];
    const float* ea       = (const float*)d_in[2];
    const int*   batch    = (const int*)d_in[3];
    const float* pocket   = (const float*)d_in[4];
    const float* W_e1     = (const float*)d_in[5];
    const float* b_e1     = (const float*)d_in[6];
    const float* W_e2     = (const float*)d_in[7];
    const float* b_e2     = (const float*)d_in[8];
    const float* root     = (const float*)d_in[9];
    const float* conv_b   = (const float*)d_in[10];
    const float* Wg       = (const float*)d_in[11];
    const float* bg       = (const float*)d_in[12];
    const float* W_fc1    = (const float*)d_in[13];
    const float* b_fc1    = (const float*)d_in[14];
    const float* W_np     = (const float*)d_in[15];
    const float* b_np     = (const float*)d_in[16];
    const float* W_sp     = (const float*)d_in[17];
    const float* b_sp     = (const float*)d_in[18];

    char* wsb = (char*)d_ws;
    float* agg    = (float*)wsb;                         // NN*64 (atomic fallback only)
    int*   base   = (int*)(agg + (size_t)NN * 64);       // NN+4
    int*   bsum   = base + NN + 4;                       // 256
    int*   cursor = bsum + 256;                          // NN
    int*   rank   = cursor + NN;                         // EE
    float* gate   = (float*)(rank + EE);                 // NN
    float* pg     = gate + NN;                           // GG*64
    float* sg     = pg + (size_t)GG * 64;                // GG
    unsigned short* hn16  = (unsigned short*)(sg + GG);  // NN*64 u16
    unsigned short* W2T   = hn16 + (size_t)NN * 64;      // 64*W2ROW
    unsigned short* W1aT  = W2T + (size_t)64 * W2ROW;    // 4096
    unsigned short* W_npT = W1aT + 4096;                 // 4096
    size_t head = (size_t)((char*)(W_npT + 4096) - wsb);
    size_t msg_off = (head + 255) & ~(size_t)255;
    unsigned* msg16 = (unsigned*)(wsb + msg_off);        // EE*32 u32
    size_t need = msg_off + (size_t)EE * 32 * sizeof(unsigned);
    const bool twophase = (ws_size >= need);

    k0_prep<<<(64 * W2ROW + 8192 + NN + 255) / 256, 256, 0, stream>>>(
        W_e2, b_e2, W_fc1, W_np, W2T, W1aT, W_npT, cursor);

    kE_local<<<(EE + 255) / 256, 256, 0, stream>>>(ei, cursor, rank);
    kB_scan1<<<NBLK, 256, 0, stream>>>(cursor, base, bsum);
    kC_scan2<<<1, 256, 0, stream>>>(bsum);
    kD_scan3<<<(NN + 255) / 256, 256, 0, stream>>>(base, bsum);

    if (twophase) {
        k1_mfma<true><<<(EE + 255) / 256, 256, 0, stream>>>(
            x, ei, ea, W_e1, b_e1, W2T, rank, base, msg16, agg);
        k2_red<<<NN / 4, 256, 0, stream>>>(msg16, base, x, root, conv_b,
                                           hn16, Wg, bg, gate);
    } else {
        hipMemsetAsync(agg, 0, (size_t)NN * 64 * sizeof(float), stream);
        k1_mfma<false><<<(EE + 255) / 256, 256, 0, stream>>>(
            x, ei, ea, W_e1, b_e1, W2T, rank, base, msg16, agg);
        k2_node<<<NN / 4, 256, 0, stream>>>(agg, base, x, root, conv_b, hn16, Wg, bg, gate);
    }

    k3_pool<<<GG, 64, 0, stream>>>(gate, batch, hn16, pocket, W_fc1, b_fc1, W_sp, b_sp, pg, sg);

    float* out_np   = (float*)d_out;
    float* out_stop = out_np + (size_t)NN * CC;
    k4_mfma<<<(NN + 127) / 128, 256, 0, stream>>>(hn16, batch, pg, sg, W1aT, W_npT, b_np,
                                                  out_np, out_stop);
}

// Round 11
// 297.508 us; speedup vs baseline: 1.3049x; 1.0636x over previous
//
#include <hip/hip_runtime.h>
#include <hip/hip_bf16.h>
#include <math.h>

#define NN 150000
#define EE 600000
#define GG 5000
#define NI 16
#define EI 8
#define GFD 32
#define HH 64
#define CC 40

#define W2SZ (68 * 1024)   // 68 chunks (64 real + bias + 3 pad) x 64 rows x 16 k, chunk-major
#define FPAD 68
#define NBLK ((NN + 1023) / 1024)

typedef __attribute__((ext_vector_type(8))) short short8v;
typedef __attribute__((ext_vector_type(16))) float f32x16;
typedef __attribute__((ext_vector_type(2))) float f32x2;

__device__ __forceinline__ unsigned short f2bf(float f) {
    __hip_bfloat16 h = __float2bfloat16(f);
    return __builtin_bit_cast(unsigned short, h);
}
__device__ __forceinline__ float bf2f(unsigned short u) {
    return __uint_as_float(((unsigned)u) << 16);
}
__device__ __forceinline__ unsigned cvtpk(float lo, float hi) {
    unsigned r;
    asm("v_cvt_pk_bf16_f32 %0, %1, %2" : "=v"(r) : "v"(lo), "v"(hi));
    return r;
}
__device__ __forceinline__ f32x2 pkmul(f32x2 a, f32x2 b) {
    f32x2 p;
    asm("v_pk_mul_f32 %0, %1, %2" : "=v"(p) : "v"(a), "v"(b));
    return p;
}
__device__ __forceinline__ short8v zfrag(float eh, const f32x2 (&xs2)[4]) {
    f32x2 ehp; ehp[0] = eh; ehp[1] = eh;
    union { short8v v; unsigned u[4]; } A;
    #pragma unroll
    for (int q = 0; q < 4; ++q) {
        f32x2 p = pkmul(ehp, xs2[q]);
        A.u[q] = cvtpk(p[0], p[1]);
    }
    return A.v;
}
__device__ __forceinline__ short8v xfrag(const f32x2 (&xs2)[4]) {
    union { short8v v; unsigned u[4]; } A;
    #pragma unroll
    for (int q = 0; q < 4; ++q)
        A.u[q] = cvtpk(xs2[q][0], xs2[q][1]);
    return A.v;
}

// ---------------- K0: prep bf16 weight views (W2 chunk-major) + zero cursor ----------------
__global__ void k0_prep(const float* __restrict__ W_e2, const float* __restrict__ b_e2,
                        const float* __restrict__ W_fc1, const float* __restrict__ W_np,
                        unsigned short* __restrict__ W2c,
                        unsigned short* __restrict__ W1aT,
                        unsigned short* __restrict__ W_npT,
                        int* __restrict__ cursor)
{
    int idx = blockIdx.x * 256 + threadIdx.x;
    if (idx < W2SZ) {
        int c = idx >> 10, rem = idx & 1023;
        int r = rem >> 4, kk = rem & 15;
        float v = 0.f;
        if (c < 64)       v = W_e2[c * 1024 + kk * 64 + r];
        else if (c == 64) v = b_e2[kk * 64 + r];
        W2c[idx] = f2bf(v);
    } else if (idx < W2SZ + 4096) {
        int i = idx - W2SZ;
        int h = i >> 6, k = i & 63;
        W1aT[i] = f2bf(W_fc1[k * 64 + h]);
    } else if (idx < W2SZ + 8192) {
        int i = idx - W2SZ - 4096;
        int c = i >> 6, h = i & 63;
        W_npT[i] = f2bf(c < CC ? W_np[h * CC + c] : 0.f);
    } else if (idx < W2SZ + 8192 + NN) {
        cursor[idx - W2SZ - 8192] = 0;
    }
}

// ---------------- kE_local: local rank within dst + counts (single atomic pass) ----------------
__global__ void kE_local(const int* __restrict__ ei, int* __restrict__ cursor,
                         int* __restrict__ rank)
{
    int e = blockIdx.x * 256 + threadIdx.x;
    if (e < EE) rank[e] = atomicAdd(&cursor[ei[EE + e]], 1);
}

// ---------------- scan of counts -> base ----------------
__global__ void kB_scan1(const int* __restrict__ cnt, int* __restrict__ base,
                         int* __restrict__ bsum)
{
    __shared__ int sS[256];
    int b = blockIdx.x, t = threadIdx.x;
    int i0 = b * 1024 + t * 4;
    int v0 = (i0 + 0 < NN) ? cnt[i0 + 0] : 0;
    int v1 = (i0 + 1 < NN) ? cnt[i0 + 1] : 0;
    int v2 = (i0 + 2 < NN) ? cnt[i0 + 2] : 0;
    int v3 = (i0 + 3 < NN) ? cnt[i0 + 3] : 0;
    int tot = v0 + v1 + v2 + v3;
    sS[t] = tot;
    __syncthreads();
    int acc = tot;
    for (int off = 1; off < 256; off <<= 1) {
        int xv = (t >= off) ? sS[t - off] : 0;
        __syncthreads();
        acc += xv;
        sS[t] = acc;
        __syncthreads();
    }
    int run = acc - tot;
    if (i0 + 0 < NN) base[i0 + 0] = run; run += v0;
    if (i0 + 1 < NN) base[i0 + 1] = run; run += v1;
    if (i0 + 2 < NN) base[i0 + 2] = run; run += v2;
    if (i0 + 3 < NN) base[i0 + 3] = run;
    if (t == 255) bsum[b] = acc;
}

__global__ void kC_scan2(int* __restrict__ bsum)
{
    __shared__ int sS[256];
    int t = threadIdx.x;
    int v = (t < NBLK) ? bsum[t] : 0;
    sS[t] = v;
    __syncthreads();
    int acc = v;
    for (int off = 1; off < 256; off <<= 1) {
        int xv = (t >= off) ? sS[t - off] : 0;
        __syncthreads();
        acc += xv;
        sS[t] = acc;
        __syncthreads();
    }
    if (t < NBLK) bsum[t] = acc - v;   // exclusive
}

__global__ void kD_scan3(int* __restrict__ base, const int* __restrict__ bsum)
{
    int i = blockIdx.x * 256 + threadIdx.x;
    if (i < NN) base[i] = base[i] + bsum[i >> 10];
    if (i == 0) base[NN] = EE;
}

// ---------------- shared MFMA inner step (chunk-major B: coalesced 2KB/step) ----------------
__device__ __forceinline__ void mfma_step(
    const unsigned short (&sEHT)[65][256], int c, int pf,
    const unsigned short* __restrict__ Bq0, const unsigned short* __restrict__ Bq1,
    int mb, int mr, const f32x2 (&xs0)[4], const f32x2 (&xs1)[4],
    short8v& curb0, short8v& curb1,
    f32x16& acc00, f32x16& acc01, f32x16& acc10, f32x16& acc11)
{
    short8v n0 = *(const short8v*)(Bq0 + pf * 1024);
    short8v n1 = *(const short8v*)(Bq1 + pf * 1024);
    int cc = (c & 31) << 1;
    float eh0 = bf2f(sEHT[c][(mb + mr) ^ cc]);
    float eh1 = bf2f(sEHT[c][(mb + 32 + mr) ^ cc]);
    short8v a0 = zfrag(eh0, xs0);
    short8v a1 = zfrag(eh1, xs1);
    __builtin_amdgcn_s_setprio(1);
    acc00 = __builtin_amdgcn_mfma_f32_32x32x16_bf16(a0, curb0, acc00, 0, 0, 0);
    acc01 = __builtin_amdgcn_mfma_f32_32x32x16_bf16(a0, curb1, acc01, 0, 0, 0);
    acc10 = __builtin_amdgcn_mfma_f32_32x32x16_bf16(a1, curb0, acc10, 0, 0, 0);
    acc11 = __builtin_amdgcn_mfma_f32_32x32x16_bf16(a1, curb1, acc11, 0, 0, 0);
    __builtin_amdgcn_s_setprio(0);
    curb0 = n0; curb1 = n1;
}

// ---------------- K1: edge MLP + MFMA z-GEMM; TWOPHASE: bf16 paired store, else atomic ----------------
template<bool TWOPHASE>
__global__ __launch_bounds__(256, 4) void k1_mfma(
    const float* __restrict__ x, const int* __restrict__ ei,
    const float* __restrict__ ea,
    const float* __restrict__ W_e1, const float* __restrict__ b_e1,
    const unsigned short* __restrict__ W2c,
    const int* __restrict__ rank, const int* __restrict__ base,
    unsigned* __restrict__ msg16, float* __restrict__ agg)
{
    __shared__ unsigned short sEHT[65][256];
    __shared__ int sIdx[256];

    const int t = threadIdx.x;
    const long long eb = (long long)blockIdx.x * 256;

    {
        long long ge = eb + t;
        if (ge < EE) {
            int d = ei[EE + ge];
            sIdx[t] = TWOPHASE ? (base[d] + rank[ge]) : d;
        } else {
            sIdx[t] = -1;
        }
        sEHT[64][t] = (unsigned short)0x3F80;   // bias row eh = 1.0
    }
    {
        const int k = t & 63;
        const int w = t >> 6;
        float w1[8];
        float b1 = b_e1[k];
        #pragma unroll
        for (int j = 0; j < 8; ++j) w1[j] = W_e1[j * 64 + k];
        #pragma unroll 4
        for (int r = 0; r < 64; ++r) {
            int e = w * 64 + r;
            long long ge = eb + e;
            float v = 0.f;
            if (ge < EE) {
                const float4* eap = (const float4*)(ea + ge * EI);
                float4 u0 = eap[0], u1 = eap[1];
                v = b1;
                v = fmaf(u0.x, w1[0], v); v = fmaf(u0.y, w1[1], v);
                v = fmaf(u0.z, w1[2], v); v = fmaf(u0.w, w1[3], v);
                v = fmaf(u1.x, w1[4], v); v = fmaf(u1.y, w1[5], v);
                v = fmaf(u1.z, w1[6], v); v = fmaf(u1.w, w1[7], v);
                v = fmaxf(v, 0.f);
            }
            sEHT[k][e ^ ((k & 31) << 1)] = f2bf(v);
        }
    }

    const int lane = t & 63;
    const int w = t >> 6;
    const int mr = lane & 31;
    const int half = lane >> 5;
    const int mb = w * 64;

    f32x2 xs0[4], xs1[4];
    {
        long long e0 = eb + mb + mr;
        long long e1 = eb + mb + 32 + mr;
        if (e0 < EE) {
            int s0 = ei[e0];
            const float4* xp = (const float4*)(x + (size_t)s0 * NI + half * 8);
            float4 u0 = xp[0], u1 = xp[1];
            xs0[0][0]=u0.x; xs0[0][1]=u0.y; xs0[1][0]=u0.z; xs0[1][1]=u0.w;
            xs0[2][0]=u1.x; xs0[2][1]=u1.y; xs0[3][0]=u1.z; xs0[3][1]=u1.w;
        } else {
            #pragma unroll
            for (int q = 0; q < 4; ++q) { xs0[q][0] = 0.f; xs0[q][1] = 0.f; }
        }
        if (e1 < EE) {
            int s1 = ei[e1];
            const float4* xp = (const float4*)(x + (size_t)s1 * NI + half * 8);
            float4 u0 = xp[0], u1 = xp[1];
            xs1[0][0]=u0.x; xs1[0][1]=u0.y; xs1[1][0]=u0.z; xs1[1][1]=u0.w;
            xs1[2][0]=u1.x; xs1[2][1]=u1.y; xs1[3][0]=u1.z; xs1[3][1]=u1.w;
        } else {
            #pragma unroll
            for (int q = 0; q < 4; ++q) { xs1[q][0] = 0.f; xs1[q][1] = 0.f; }
        }
    }
    __syncthreads();

    f32x16 acc00, acc01, acc10, acc11;
    #pragma unroll
    for (int r = 0; r < 16; ++r) { acc00[r] = 0.f; acc01[r] = 0.f; acc10[r] = 0.f; acc11[r] = 0.f; }

    // chunk-major B: wave's two loads per step cover the chunk's contiguous 2KB
    const unsigned short* Bq0 = W2c + mr * 16 + half * 8;          // rows 0..31
    const unsigned short* Bq1 = Bq0 + 512;                         // rows 32..63

    short8v bA0 = *(const short8v*)(Bq0);
    short8v bA1 = *(const short8v*)(Bq1);
    short8v bB0 = *(const short8v*)(Bq0 + 1024);
    short8v bB1 = *(const short8v*)(Bq1 + 1024);

    #pragma unroll 2
    for (int c = 0; c < 64; c += 2) {
        mfma_step(sEHT, c,     c + 2, Bq0, Bq1, mb, mr, xs0, xs1, bA0, bA1, acc00, acc01, acc10, acc11);
        mfma_step(sEHT, c + 1, c + 3, Bq0, Bq1, mb, mr, xs0, xs1, bB0, bB1, acc00, acc01, acc10, acc11);
    }
    // bias chunk c=64: eh = 1 -> A = bf16(xs); B in bA (prefetched at c=62)
    {
        short8v a0 = xfrag(xs0);
        short8v a1 = xfrag(xs1);
        __builtin_amdgcn_s_setprio(1);
        acc00 = __builtin_amdgcn_mfma_f32_32x32x16_bf16(a0, bA0, acc00, 0, 0, 0);
        acc01 = __builtin_amdgcn_mfma_f32_32x32x16_bf16(a0, bA1, acc01, 0, 0, 0);
        acc10 = __builtin_amdgcn_mfma_f32_32x32x16_bf16(a1, bA0, acc10, 0, 0, 0);
        acc11 = __builtin_amdgcn_mfma_f32_32x32x16_bf16(a1, bA1, acc11, 0, 0, 0);
        __builtin_amdgcn_s_setprio(0);
    }

    #pragma unroll
    for (int r = 0; r < 16; ++r) {
        int row = (r & 3) + 8 * (r >> 2) + 4 * half;
        int i0 = sIdx[mb + row];
        int i1 = sIdx[mb + 32 + row];
        if (TWOPHASE) {
            if (i0 >= 0) msg16[(size_t)i0 * 32 + mr] = cvtpk(acc00[r], acc01[r]);
            if (i1 >= 0) msg16[(size_t)i1 * 32 + mr] = cvtpk(acc10[r], acc11[r]);
        } else {
            if (i0 >= 0) {
                atomicAdd(&agg[(size_t)i0 * 64 + mr],      acc00[r]);
                atomicAdd(&agg[(size_t)i0 * 64 + 32 + mr], acc01[r]);
            }
            if (i1 >= 0) {
                atomicAdd(&agg[(size_t)i1 * 64 + mr],      acc10[r]);
                atomicAdd(&agg[(size_t)i1 * 64 + 32 + mr], acc11[r]);
            }
        }
    }
}

// ---------------- K2 (two-phase): stream-reduce bf16 msg16 + mean + root + relu + gate ----------------
__global__ __launch_bounds__(256) void k2_red(
    const unsigned* __restrict__ msg16, const int* __restrict__ base,
    const float* __restrict__ x, const float* __restrict__ root,
    const float* __restrict__ conv_bias,
    unsigned short* __restrict__ hn16,
    const float* __restrict__ Wg, const float* __restrict__ bg,
    float* __restrict__ gate)
{
    __shared__ float sroot[16][64];
    int t = threadIdx.x;
    #pragma unroll
    for (int q = 0; q < 4; ++q) {
        int i = q * 256 + t;
        sroot[i >> 6][i & 63] = root[i];
    }
    __syncthreads();

    int n = blockIdx.x * 4 + (t >> 6);
    int l = t & 63;
    int mr = l & 31, so = l >> 5;
    int s = base[n], e = base[n + 1];

    float alo = 0.f, ahi = 0.f;
    for (int sl = s + so; sl < e; sl += 2) {
        unsigned u = msg16[(size_t)sl * 32 + mr];
        alo += __uint_as_float(u << 16);
        ahi += __uint_as_float(u & 0xFFFF0000u);
    }
    alo += __shfl_xor(alo, 32);
    ahi += __shfl_xor(ahi, 32);
    float acc = (l < 32) ? alo : ahi;

    float inv = 1.0f / fmaxf((float)(e - s), 1.0f);
    float v = acc * inv + conv_bias[l];
    float xv = (l < 16) ? x[(size_t)n * NI + l] : 0.f;
    #pragma unroll
    for (int i = 0; i < 16; ++i)
        v = fmaf(__shfl(xv, i), sroot[i][l], v);
    v = fmaxf(v, 0.f);
    hn16[(size_t)n * 64 + l] = f2bf(v);

    float gv = v * Wg[l];
    #pragma unroll
    for (int off = 32; off; off >>= 1) gv += __shfl_xor(gv, off);
    if (l == 0) gate[n] = gv + bg[0];
}

// ---------------- K2 (fallback): mean + root + relu over agg ----------------
__global__ __launch_bounds__(256) void k2_node(
    const float* __restrict__ agg, const int* __restrict__ base,
    const float* __restrict__ x, const float* __restrict__ root,
    const float* __restrict__ conv_bias,
    unsigned short* __restrict__ hn16,
    const float* __restrict__ Wg, const float* __restrict__ bg,
    float* __restrict__ gate)
{
    int t = threadIdx.x;
    int n = blockIdx.x * 4 + (t >> 6);
    int h = t & 63;
    float cntv = (float)(base[n + 1] - base[n]);
    float inv = 1.0f / fmaxf(cntv, 1.0f);
    float v = agg[(size_t)n * 64 + h] * inv + conv_bias[h];
    const float* xp = x + (size_t)n * NI;
    #pragma unroll
    for (int i = 0; i < NI; ++i) v += xp[i] * root[i * 64 + h];
    v = fmaxf(v, 0.f);
    hn16[(size_t)n * 64 + h] = f2bf(v);
    float gv = v * Wg[h];
    #pragma unroll
    for (int off = 32; off; off >>= 1) gv += __shfl_xor(gv, off);
    if (h == 0) gate[n] = gv + bg[0];
}

// ---------------- K3: per-graph pooling + pg/sg precompute ----------------
__device__ __forceinline__ int lbound(const int* __restrict__ b, int v) {
    int lo = 0, hi = NN;
    while (lo < hi) { int mid = (lo + hi) >> 1; if (b[mid] < v) lo = mid + 1; else hi = mid; }
    return lo;
}

__global__ __launch_bounds__(64) void k3_pool(
    const float* __restrict__ gate, const int* __restrict__ batch,
    const unsigned short* __restrict__ hn16, const float* __restrict__ pocket,
    const float* __restrict__ W_fc1, const float* __restrict__ b_fc1,
    const float* __restrict__ W_sp, const float* __restrict__ b_sp,
    float* __restrict__ pg, float* __restrict__ sg)
{
    int g = blockIdx.x;
    int lane = threadIdx.x;
    int s = lbound(batch, g);
    int e = lbound(batch, g + 1);

    float gcv = 0.f;
    if (e > s) {
        float m = -INFINITY;
        for (int n = s + lane; n < e; n += 64) m = fmaxf(m, gate[n]);
        #pragma unroll
        for (int off = 32; off; off >>= 1) m = fmaxf(m, __shfl_xor(m, off));
        float acc = 0.f, den = 0.f;
        for (int n = s; n < e; ++n) {
            float ev = expf(gate[n] - m);
            den += ev;
            acc += ev * bf2f(hn16[(size_t)n * 64 + lane]);
        }
        gcv = acc / den;
    }

    float sv = gcv * W_sp[lane];
    #pragma unroll
    for (int off = 32; off; off >>= 1) sv += __shfl_xor(sv, off);
    if (lane == 0) sg[g] = 1.f / (1.f + expf(-(sv + b_sp[0])));

    float pk = (lane < GFD) ? pocket[(size_t)g * GFD + lane] : 0.f;
    float pgv = b_fc1[lane];
    #pragma unroll 8
    for (int kk = 0; kk < 64; ++kk)
        pgv = fmaf(__shfl(gcv, kk), W_fc1[(64 + kk) * 64 + lane], pgv);
    #pragma unroll 8
    for (int kk = 0; kk < 32; ++kk)
        pgv = fmaf(__shfl(pk, kk), W_fc1[(128 + kk) * 64 + lane], pgv);
    pg[(size_t)g * 64 + lane] = pgv;
}

// ---------------- K4: MFMA head ----------------
__global__ __launch_bounds__(256, 4) void k4_mfma(
    const unsigned short* __restrict__ hn16, const int* __restrict__ batch,
    const float* __restrict__ pg, const float* __restrict__ sg,
    const unsigned short* __restrict__ W1aT, const unsigned short* __restrict__ W_npT,
    const float* __restrict__ b_np,
    float* __restrict__ out_np, float* __restrict__ out_stop)
{
    __shared__ __align__(16) float sF[4][32][FPAD];
    __shared__ int sB[128];

    const int t = threadIdx.x;
    const int wv = t >> 6, lane = t & 63;
    const int mr = lane & 31, half = lane >> 5;
    const int nb = blockIdx.x * 128;

    if (t < 128) {
        int n = nb + t;
        sB[t] = (n < NN) ? batch[n] : 0;
    }

    const int node = nb + wv * 32 + mr;

    f32x16 acc0, acc1;
    #pragma unroll
    for (int r = 0; r < 16; ++r) { acc0[r] = 0.f; acc1[r] = 0.f; }

    #pragma unroll
    for (int c = 0; c < 4; ++c) {
        short8v a;
        if (node < NN) {
            a = *(const short8v*)(hn16 + (size_t)node * 64 + c * 16 + half * 8);
        } else {
            #pragma unroll
            for (int q = 0; q < 8; ++q) a[q] = 0;
        }
        short8v b0 = *(const short8v*)(W1aT + (size_t)mr * 64        + c * 16 + half * 8);
        short8v b1 = *(const short8v*)(W1aT + (size_t)(mr + 32) * 64 + c * 16 + half * 8);
        acc0 = __builtin_amdgcn_mfma_f32_32x32x16_bf16(a, b0, acc0, 0, 0, 0);
        acc1 = __builtin_amdgcn_mfma_f32_32x32x16_bf16(a, b1, acc1, 0, 0, 0);
    }
    __syncthreads();

    #pragma unroll
    for (int r = 0; r < 16; ++r) {
        int row = (r & 3) + 8 * (r >> 2) + 4 * half;
        int g = sB[wv * 32 + row];
        float p0 = pg[(size_t)g * 64 + mr];
        float p1 = pg[(size_t)g * 64 + 32 + mr];
        sF[wv][row][mr]      = fmaxf(acc0[r] + p0, 0.f);
        sF[wv][row][32 + mr] = fmaxf(acc1[r] + p1, 0.f);
    }

    f32x16 acc2, acc3;
    #pragma unroll
    for (int r = 0; r < 16; ++r) { acc2[r] = 0.f; acc3[r] = 0.f; }

    #pragma unroll
    for (int c = 0; c < 4; ++c) {
        const float* fp = &sF[wv][mr][c * 16 + half * 8];
        float4 u0 = *(const float4*)(fp);
        float4 u1 = *(const float4*)(fp + 4);
        union { short8v v; unsigned u[4]; } A;
        A.u[0] = cvtpk(u0.x, u0.y); A.u[1] = cvtpk(u0.z, u0.w);
        A.u[2] = cvtpk(u1.x, u1.y); A.u[3] = cvtpk(u1.z, u1.w);
        short8v a = A.v;
        short8v b0 = *(const short8v*)(W_npT + (size_t)mr * 64        + c * 16 + half * 8);
        short8v b1 = *(const short8v*)(W_npT + (size_t)(mr + 32) * 64 + c * 16 + half * 8);
        acc2 = __builtin_amdgcn_mfma_f32_32x32x16_bf16(a, b0, acc2, 0, 0, 0);
        acc3 = __builtin_amdgcn_mfma_f32_32x32x16_bf16(a, b1, acc3, 0, 0, 0);
    }

    float bn1 = b_np[mr];
    float bn2 = (mr < 8) ? b_np[32 + mr] : 0.f;

    #pragma unroll
    for (int r = 0; r < 16; ++r) {
        int row = (r & 3) + 8 * (r >> 2) + 4 * half;
        int n = nb + wv * 32 + row;
        float v1 = acc2[r] + bn1;
        float v2 = acc3[r] + bn2;
        float m = (mr < 8) ? fmaxf(v1, v2) : v1;
        #pragma unroll
        for (int off = 16; off; off >>= 1) m = fmaxf(m, __shfl_xor(m, off));
        float s = expf(v1 - m) + ((mr < 8) ? expf(v2 - m) : 0.f);
        #pragma unroll
        for (int off = 16; off; off >>= 1) s += __shfl_xor(s, off);
        float ls = m + logf(s);
        if (n < NN) {
            out_np[(size_t)n * CC + mr] = v1 - ls;
            if (mr < 8) out_np[(size_t)n * CC + 32 + mr] = v2 - ls;
            if (mr == 0) out_stop[n] = sg[sB[wv * 32 + row]];
        }
    }
}

extern "C" void kernel_launch(void* const* d_in, const int* in_sizes, int n_in,
                              void* d_out, int out_size, void* d_ws, size_t ws_size,
                              hipStream_t stream)
{
    (void)in_sizes; (void)n_in; (void)out_size;
    const float* x        = (const float*)d_in[0];
    const int*   ei       = (const int*)d_in[1];
    const float* ea       = (const float*)d_in[2];
    const int*   batch    = (const int*)d_in[3];
    const float* pocket   = (const float*)d_in[4];
    const float* W_e1     = (const float*)d_in[5];
    const float* b_e1     = (const float*)d_in[6];
    const float* W_e2     = (const float*)d_in[7];
    const float* b_e2     = (const float*)d_in[8];
    const float* root     = (const float*)d_in[9];
    const float* conv_b   = (const float*)d_in[10];
    const float* Wg       = (const float*)d_in[11];
    const float* bg       = (const float*)d_in[12];
    const float* W_fc1    = (const float*)d_in[13];
    const float* b_fc1    = (const float*)d_in[14];
    const float* W_np     = (const float*)d_in[15];
    const float* b_np     = (const float*)d_in[16];
    const float* W_sp     = (const float*)d_in[17];
    const float* b_sp     = (const float*)d_in[18];

    char* wsb = (char*)d_ws;
    float* agg    = (float*)wsb;                         // NN*64 (atomic fallback only)
    int*   base   = (int*)(agg + (size_t)NN * 64);       // NN+4
    int*   bsum   = base + NN + 4;                       // 256
    int*   cursor = bsum + 256;                          // NN
    int*   rank   = cursor + NN;                         // EE
    float* gate   = (float*)(rank + EE);                 // NN
    float* pg     = gate + NN;                           // GG*64
    float* sg     = pg + (size_t)GG * 64;                // GG
    unsigned short* hn16  = (unsigned short*)(sg + GG);  // NN*64 u16
    unsigned short* W2c   = hn16 + (size_t)NN * 64;      // W2SZ
    unsigned short* W1aT  = W2c + W2SZ;                  // 4096
    unsigned short* W_npT = W1aT + 4096;                 // 4096
    size_t head = (size_t)((char*)(W_npT + 4096) - wsb);
    size_t msg_off = (head + 255) & ~(size_t)255;
    unsigned* msg16 = (unsigned*)(wsb + msg_off);        // EE*32 u32
    size_t need = msg_off + (size_t)EE * 32 * sizeof(unsigned);
    const bool twophase = (ws_size >= need);

    k0_prep<<<(W2SZ + 8192 + NN + 255) / 256, 256, 0, stream>>>(
        W_e2, b_e2, W_fc1, W_np, W2c, W1aT, W_npT, cursor);

    kE_local<<<(EE + 255) / 256, 256, 0, stream>>>(ei, cursor, rank);
    kB_scan1<<<NBLK, 256, 0, stream>>>(cursor, base, bsum);
    kC_scan2<<<1, 256, 0, stream>>>(bsum);
    kD_scan3<<<(NN + 255) / 256, 256, 0, stream>>>(base, bsum);

    if (twophase) {
        k1_mfma<true><<<(EE + 255) / 256, 256, 0, stream>>>(
            x, ei, ea, W_e1, b_e1, W2c, rank, base, msg16, agg);
        k2_red<<<NN / 4, 256, 0, stream>>>(msg16, base, x, root, conv_b,
                                           hn16, Wg, bg, gate);
    } else {
        hipMemsetAsync(agg, 0, (size_t)NN * 64 * sizeof(float), stream);
        k1_mfma<false><<<(EE + 255) / 256, 256, 0, stream>>>(
            x, ei, ea, W_e1, b_e1, W2c, rank, base, msg16, agg);
        k2_node<<<NN / 4, 256, 0, stream>>>(agg, base, x, root, conv_b, hn16, Wg, bg, gate);
    }

    k3_pool<<<GG, 64, 0, stream>>>(gate, batch, hn16, pocket, W_fc1, b_fc1, W_sp, b_sp, pg, sg);

    float* out_np   = (float*)d_out;
    float* out_stop = out_np + (size_t)NN * CC;
    k4_mfma<<<(NN + 127) / 128, 256, 0, stream>>>(hn16, batch, pg, sg, W1aT, W_npT, b_np,
                                                  out_np, out_stop);
}

// Round 12
// 259.876 us; speedup vs baseline: 1.4939x; 1.1448x over previous
//
#include <hip/hip_runtime.h>
#include <hip/hip_bf16.h>
#include <math.h>

#define NN 150000
#define EE 600000
#define GG 5000
#define NI 16
#define EI 8
#define GFD 32
#define HH 64
#define CC 40

#define W2SZ (68 * 1024)   // 68 chunks (64 real + bias + 3 pad) x 64 rows x 16 k, chunk-major
#define FPAD 68
#define NBLK ((NN + 1023) / 1024)

typedef __attribute__((ext_vector_type(8))) short short8v;
typedef __attribute__((ext_vector_type(16))) float f32x16;
typedef __attribute__((ext_vector_type(2))) float f32x2;

__device__ __forceinline__ unsigned short f2bf(float f) {
    __hip_bfloat16 h = __float2bfloat16(f);
    return __builtin_bit_cast(unsigned short, h);
}
__device__ __forceinline__ float bf2f(unsigned short u) {
    return __uint_as_float(((unsigned)u) << 16);
}
__device__ __forceinline__ unsigned cvtpk(float lo, float hi) {
    unsigned r;
    asm("v_cvt_pk_bf16_f32 %0, %1, %2" : "=v"(r) : "v"(lo), "v"(hi));
    return r;
}
__device__ __forceinline__ f32x2 pkmul(f32x2 a, f32x2 b) {
    f32x2 p;
    asm("v_pk_mul_f32 %0, %1, %2" : "=v"(p) : "v"(a), "v"(b));
    return p;
}
__device__ __forceinline__ short8v zfrag(float eh, const f32x2 (&xs2)[4]) {
    f32x2 ehp; ehp[0] = eh; ehp[1] = eh;
    union { short8v v; unsigned u[4]; } A;
    #pragma unroll
    for (int q = 0; q < 4; ++q) {
        f32x2 p = pkmul(ehp, xs2[q]);
        A.u[q] = cvtpk(p[0], p[1]);
    }
    return A.v;
}
__device__ __forceinline__ short8v xfrag(const f32x2 (&xs2)[4]) {
    union { short8v v; unsigned u[4]; } A;
    #pragma unroll
    for (int q = 0; q < 4; ++q)
        A.u[q] = cvtpk(xs2[q][0], xs2[q][1]);
    return A.v;
}

// ---------------- K0: prep bf16 weight views + zero cursor ----------------
__global__ void k0_prep(const float* __restrict__ W_e2, const float* __restrict__ b_e2,
                        const float* __restrict__ W_fc1, const float* __restrict__ W_np,
                        const float* __restrict__ W_e1,
                        unsigned short* __restrict__ W2c,
                        unsigned short* __restrict__ W1aT,
                        unsigned short* __restrict__ W_npT,
                        unsigned short* __restrict__ W1e,
                        int* __restrict__ cursor)
{
    int idx = blockIdx.x * 256 + threadIdx.x;
    if (idx < W2SZ) {
        int c = idx >> 10, rem = idx & 1023;
        int r = rem >> 4, kk = rem & 15;
        float v = 0.f;
        if (c < 64)       v = W_e2[c * 1024 + kk * 64 + r];
        else if (c == 64) v = b_e2[kk * 64 + r];
        W2c[idx] = f2bf(v);
    } else if (idx < W2SZ + 4096) {
        int i = idx - W2SZ;
        int h = i >> 6, k = i & 63;
        W1aT[i] = f2bf(W_fc1[k * 64 + h]);
    } else if (idx < W2SZ + 8192) {
        int i = idx - W2SZ - 4096;
        int c = i >> 6, h = i & 63;
        W_npT[i] = f2bf(c < CC ? W_np[h * CC + c] : 0.f);
    } else if (idx < W2SZ + 8704) {
        int i = idx - W2SZ - 8192;   // W1e[col][q] = W_e1[q][col]
        int col = i >> 3, q = i & 7;
        W1e[i] = f2bf(W_e1[q * 64 + col]);
    } else if (idx < W2SZ + 8704 + NN) {
        cursor[idx - W2SZ - 8704] = 0;
    }
}

// ---------------- kE_local: local rank within dst + counts (single atomic pass) ----------------
__global__ void kE_local(const int* __restrict__ ei, int* __restrict__ cursor,
                         int* __restrict__ rank)
{
    int e = blockIdx.x * 256 + threadIdx.x;
    if (e < EE) rank[e] = atomicAdd(&cursor[ei[EE + e]], 1);
}

// ---------------- scan of counts -> base (block-local; consumers add bsum[i>>10]) ----------------
__global__ void kB_scan1(const int* __restrict__ cnt, int* __restrict__ base,
                         int* __restrict__ bsum)
{
    __shared__ int sS[256];
    int b = blockIdx.x, t = threadIdx.x;
    int i0 = b * 1024 + t * 4;
    int v0 = (i0 + 0 < NN) ? cnt[i0 + 0] : 0;
    int v1 = (i0 + 1 < NN) ? cnt[i0 + 1] : 0;
    int v2 = (i0 + 2 < NN) ? cnt[i0 + 2] : 0;
    int v3 = (i0 + 3 < NN) ? cnt[i0 + 3] : 0;
    int tot = v0 + v1 + v2 + v3;
    sS[t] = tot;
    __syncthreads();
    int acc = tot;
    for (int off = 1; off < 256; off <<= 1) {
        int xv = (t >= off) ? sS[t - off] : 0;
        __syncthreads();
        acc += xv;
        sS[t] = acc;
        __syncthreads();
    }
    int run = acc - tot;
    if (i0 + 0 < NN) base[i0 + 0] = run; run += v0;
    if (i0 + 1 < NN) base[i0 + 1] = run; run += v1;
    if (i0 + 2 < NN) base[i0 + 2] = run; run += v2;
    if (i0 + 3 < NN) base[i0 + 3] = run;
    if (t == 255) bsum[b] = acc;
}

__global__ void kC_scan2(int* __restrict__ bsum)
{
    __shared__ int sS[256];
    int t = threadIdx.x;
    int v = (t < NBLK) ? bsum[t] : 0;
    sS[t] = v;
    __syncthreads();
    int acc = v;
    for (int off = 1; off < 256; off <<= 1) {
        int xv = (t >= off) ? sS[t - off] : 0;
        __syncthreads();
        acc += xv;
        sS[t] = acc;
        __syncthreads();
    }
    if (t < NBLK) bsum[t] = acc - v;   // exclusive
}

// ---------------- shared MFMA inner step (chunk-major B: coalesced 2KB/step) ----------------
__device__ __forceinline__ void mfma_step(
    const unsigned short (&sEHT)[65][256], int c, int pf,
    const unsigned short* __restrict__ Bq0, const unsigned short* __restrict__ Bq1,
    int mb, int mr, const f32x2 (&xs0)[4], const f32x2 (&xs1)[4],
    short8v& curb0, short8v& curb1,
    f32x16& acc00, f32x16& acc01, f32x16& acc10, f32x16& acc11)
{
    short8v n0 = *(const short8v*)(Bq0 + pf * 1024);
    short8v n1 = *(const short8v*)(Bq1 + pf * 1024);
    int cc = (c & 31) << 1;
    float eh0 = bf2f(sEHT[c][(mb + mr) ^ cc]);
    float eh1 = bf2f(sEHT[c][(mb + 32 + mr) ^ cc]);
    short8v a0 = zfrag(eh0, xs0);
    short8v a1 = zfrag(eh1, xs1);
    __builtin_amdgcn_s_setprio(1);
    acc00 = __builtin_amdgcn_mfma_f32_32x32x16_bf16(a0, curb0, acc00, 0, 0, 0);
    acc01 = __builtin_amdgcn_mfma_f32_32x32x16_bf16(a0, curb1, acc01, 0, 0, 0);
    acc10 = __builtin_amdgcn_mfma_f32_32x32x16_bf16(a1, curb0, acc10, 0, 0, 0);
    acc11 = __builtin_amdgcn_mfma_f32_32x32x16_bf16(a1, curb1, acc11, 0, 0, 0);
    __builtin_amdgcn_s_setprio(0);
    curb0 = n0; curb1 = n1;
}

// ---------------- K1: MFMA edge MLP + MFMA z-GEMM; TWOPHASE: bf16 paired store, else atomic ----------------
template<bool TWOPHASE>
__global__ __launch_bounds__(256, 4) void k1_mfma(
    const float* __restrict__ x, const int* __restrict__ ei,
    const float* __restrict__ ea,
    const unsigned short* __restrict__ W1e, const float* __restrict__ b_e1,
    const unsigned short* __restrict__ W2c,
    const int* __restrict__ rank, const int* __restrict__ base,
    const int* __restrict__ bsum,
    unsigned* __restrict__ msg16, float* __restrict__ agg)
{
    __shared__ unsigned short sEHT[65][256];
    __shared__ int sIdx[256];

    const int t = threadIdx.x;
    const long long eb = (long long)blockIdx.x * 256;

    const int lane = t & 63;
    const int w = t >> 6;
    const int mr = lane & 31;
    const int half = lane >> 5;
    const int mb = w * 64;

    {
        long long ge = eb + t;
        if (ge < EE) {
            int d = ei[EE + ge];
            sIdx[t] = TWOPHASE ? (base[d] + bsum[d >> 10] + rank[ge]) : d;
        } else {
            sIdx[t] = -1;
        }
        sEHT[64][t] = (unsigned short)0x3F80;   // bias row eh = 1.0
    }

    // ---- edge MLP layer 1 via MFMA: eh = relu(ea @ W_e1 + b_e1) -> sEHT ----
    {
        short8v bW0, bW1;
        if (half == 0) {
            bW0 = *(const short8v*)(W1e + (size_t)mr * 8);
            bW1 = *(const short8v*)(W1e + (size_t)(32 + mr) * 8);
        } else {
            #pragma unroll
            for (int q = 0; q < 8; ++q) { bW0[q] = 0; bW1[q] = 0; }
        }
        float bias0 = b_e1[mr];
        float bias1 = b_e1[32 + mr];
        #pragma unroll
        for (int m = 0; m < 2; ++m) {
            int e_loc = w * 64 + m * 32 + mr;
            long long ge = eb + e_loc;
            short8v a;
            if (half == 0 && ge < EE) {
                const float4* eap = (const float4*)(ea + ge * EI);
                float4 u0 = eap[0], u1 = eap[1];
                union { short8v v; unsigned u[4]; } A;
                A.u[0] = cvtpk(u0.x, u0.y); A.u[1] = cvtpk(u0.z, u0.w);
                A.u[2] = cvtpk(u1.x, u1.y); A.u[3] = cvtpk(u1.z, u1.w);
                a = A.v;
            } else {
                #pragma unroll
                for (int q = 0; q < 8; ++q) a[q] = 0;
            }
            #pragma unroll
            for (int n = 0; n < 2; ++n) {
                f32x16 c_;
                #pragma unroll
                for (int r = 0; r < 16; ++r) c_[r] = 0.f;
                c_ = __builtin_amdgcn_mfma_f32_32x32x16_bf16(a, n ? bW1 : bW0, c_, 0, 0, 0);
                int kcol = n * 32 + mr;
                float bias = n ? bias1 : bias0;
                #pragma unroll
                for (int r = 0; r < 16; r += 2) {
                    int row = (r & 3) + 8 * (r >> 2) + 4 * half;
                    int e0 = w * 64 + m * 32 + row;
                    float v0 = fmaxf(c_[r]     + bias, 0.f);
                    float v1 = fmaxf(c_[r + 1] + bias, 0.f);
                    *(unsigned*)&sEHT[kcol][e0 ^ (mr << 1)] = cvtpk(v0, v1);
                }
            }
        }
    }

    // ---- per-lane xs gather ----
    f32x2 xs0[4], xs1[4];
    {
        long long e0 = eb + mb + mr;
        long long e1 = eb + mb + 32 + mr;
        if (e0 < EE) {
            int s0 = ei[e0];
            const float4* xp = (const float4*)(x + (size_t)s0 * NI + half * 8);
            float4 u0 = xp[0], u1 = xp[1];
            xs0[0][0]=u0.x; xs0[0][1]=u0.y; xs0[1][0]=u0.z; xs0[1][1]=u0.w;
            xs0[2][0]=u1.x; xs0[2][1]=u1.y; xs0[3][0]=u1.z; xs0[3][1]=u1.w;
        } else {
            #pragma unroll
            for (int q = 0; q < 4; ++q) { xs0[q][0] = 0.f; xs0[q][1] = 0.f; }
        }
        if (e1 < EE) {
            int s1 = ei[e1];
            const float4* xp = (const float4*)(x + (size_t)s1 * NI + half * 8);
            float4 u0 = xp[0], u1 = xp[1];
            xs1[0][0]=u0.x; xs1[0][1]=u0.y; xs1[1][0]=u0.z; xs1[1][1]=u0.w;
            xs1[2][0]=u1.x; xs1[2][1]=u1.y; xs1[3][0]=u1.z; xs1[3][1]=u1.w;
        } else {
            #pragma unroll
            for (int q = 0; q < 4; ++q) { xs1[q][0] = 0.f; xs1[q][1] = 0.f; }
        }
    }
    __syncthreads();

    f32x16 acc00, acc01, acc10, acc11;
    #pragma unroll
    for (int r = 0; r < 16; ++r) { acc00[r] = 0.f; acc01[r] = 0.f; acc10[r] = 0.f; acc11[r] = 0.f; }

    const unsigned short* Bq0 = W2c + mr * 16 + half * 8;
    const unsigned short* Bq1 = Bq0 + 512;

    short8v bA0 = *(const short8v*)(Bq0);
    short8v bA1 = *(const short8v*)(Bq1);
    short8v bB0 = *(const short8v*)(Bq0 + 1024);
    short8v bB1 = *(const short8v*)(Bq1 + 1024);

    #pragma unroll 2
    for (int c = 0; c < 64; c += 2) {
        mfma_step(sEHT, c,     c + 2, Bq0, Bq1, mb, mr, xs0, xs1, bA0, bA1, acc00, acc01, acc10, acc11);
        mfma_step(sEHT, c + 1, c + 3, Bq0, Bq1, mb, mr, xs0, xs1, bB0, bB1, acc00, acc01, acc10, acc11);
    }
    // bias chunk c=64: eh = 1 -> A = bf16(xs); B in bA (prefetched at c=62)
    {
        short8v a0 = xfrag(xs0);
        short8v a1 = xfrag(xs1);
        __builtin_amdgcn_s_setprio(1);
        acc00 = __builtin_amdgcn_mfma_f32_32x32x16_bf16(a0, bA0, acc00, 0, 0, 0);
        acc01 = __builtin_amdgcn_mfma_f32_32x32x16_bf16(a0, bA1, acc01, 0, 0, 0);
        acc10 = __builtin_amdgcn_mfma_f32_32x32x16_bf16(a1, bA0, acc10, 0, 0, 0);
        acc11 = __builtin_amdgcn_mfma_f32_32x32x16_bf16(a1, bA1, acc11, 0, 0, 0);
        __builtin_amdgcn_s_setprio(0);
    }

    #pragma unroll
    for (int r = 0; r < 16; ++r) {
        int row = (r & 3) + 8 * (r >> 2) + 4 * half;
        int i0 = sIdx[mb + row];
        int i1 = sIdx[mb + 32 + row];
        if (TWOPHASE) {
            if (i0 >= 0) msg16[(size_t)i0 * 32 + mr] = cvtpk(acc00[r], acc01[r]);
            if (i1 >= 0) msg16[(size_t)i1 * 32 + mr] = cvtpk(acc10[r], acc11[r]);
        } else {
            if (i0 >= 0) {
                atomicAdd(&agg[(size_t)i0 * 64 + mr],      acc00[r]);
                atomicAdd(&agg[(size_t)i0 * 64 + 32 + mr], acc01[r]);
            }
            if (i1 >= 0) {
                atomicAdd(&agg[(size_t)i1 * 64 + mr],      acc10[r]);
                atomicAdd(&agg[(size_t)i1 * 64 + 32 + mr], acc11[r]);
            }
        }
    }
}

// ---------------- K2 (two-phase): stream-reduce bf16 msg16 + mean + root + relu + gate ----------------
__global__ __launch_bounds__(256) void k2_red(
    const unsigned* __restrict__ msg16, const int* __restrict__ base,
    const int* __restrict__ bsum,
    const float* __restrict__ x, const float* __restrict__ root,
    const float* __restrict__ conv_bias,
    unsigned short* __restrict__ hn16,
    const float* __restrict__ Wg, const float* __restrict__ bg,
    float* __restrict__ gate)
{
    __shared__ float sroot[16][64];
    int t = threadIdx.x;
    #pragma unroll
    for (int q = 0; q < 4; ++q) {
        int i = q * 256 + t;
        sroot[i >> 6][i & 63] = root[i];
    }
    __syncthreads();

    int n = blockIdx.x * 4 + (t >> 6);
    int l = t & 63;
    int mr = l & 31, so = l >> 5;
    int s = base[n] + bsum[n >> 10];
    int e = (n == NN - 1) ? EE : base[n + 1] + bsum[(n + 1) >> 10];

    float alo = 0.f, ahi = 0.f;
    for (int sl = s + so; sl < e; sl += 2) {
        unsigned u = msg16[(size_t)sl * 32 + mr];
        alo += __uint_as_float(u << 16);
        ahi += __uint_as_float(u & 0xFFFF0000u);
    }
    alo += __shfl_xor(alo, 32);
    ahi += __shfl_xor(ahi, 32);
    float acc = (l < 32) ? alo : ahi;

    float inv = 1.0f / fmaxf((float)(e - s), 1.0f);
    float v = acc * inv + conv_bias[l];
    float xv = (l < 16) ? x[(size_t)n * NI + l] : 0.f;
    #pragma unroll
    for (int i = 0; i < 16; ++i)
        v = fmaf(__shfl(xv, i), sroot[i][l], v);
    v = fmaxf(v, 0.f);
    hn16[(size_t)n * 64 + l] = f2bf(v);

    float gv = v * Wg[l];
    #pragma unroll
    for (int off = 32; off; off >>= 1) gv += __shfl_xor(gv, off);
    if (l == 0) gate[n] = gv + bg[0];
}

// ---------------- K2 (fallback): mean + root + relu over agg ----------------
__global__ __launch_bounds__(256) void k2_node(
    const float* __restrict__ agg, const int* __restrict__ base,
    const int* __restrict__ bsum,
    const float* __restrict__ x, const float* __restrict__ root,
    const float* __restrict__ conv_bias,
    unsigned short* __restrict__ hn16,
    const float* __restrict__ Wg, const float* __restrict__ bg,
    float* __restrict__ gate)
{
    int t = threadIdx.x;
    int n = blockIdx.x * 4 + (t >> 6);
    int h = t & 63;
    int s = base[n] + bsum[n >> 10];
    int e = (n == NN - 1) ? EE : base[n + 1] + bsum[(n + 1) >> 10];
    float inv = 1.0f / fmaxf((float)(e - s), 1.0f);
    float v = agg[(size_t)n * 64 + h] * inv + conv_bias[h];
    const float* xp = x + (size_t)n * NI;
    #pragma unroll
    for (int i = 0; i < NI; ++i) v += xp[i] * root[i * 64 + h];
    v = fmaxf(v, 0.f);
    hn16[(size_t)n * 64 + h] = f2bf(v);
    float gv = v * Wg[h];
    #pragma unroll
    for (int off = 32; off; off >>= 1) gv += __shfl_xor(gv, off);
    if (h == 0) gate[n] = gv + bg[0];
}

// ---------------- K3: per-graph pooling + pg/sg precompute ----------------
__device__ __forceinline__ int lbound(const int* __restrict__ b, int v) {
    int lo = 0, hi = NN;
    while (lo < hi) { int mid = (lo + hi) >> 1; if (b[mid] < v) lo = mid + 1; else hi = mid; }
    return lo;
}

__global__ __launch_bounds__(64) void k3_pool(
    const float* __restrict__ gate, const int* __restrict__ batch,
    const unsigned short* __restrict__ hn16, const float* __restrict__ pocket,
    const float* __restrict__ W_fc1, const float* __restrict__ b_fc1,
    const float* __restrict__ W_sp, const float* __restrict__ b_sp,
    float* __restrict__ pg, float* __restrict__ sg)
{
    int g = blockIdx.x;
    int lane = threadIdx.x;
    int s = lbound(batch, g);
    int e = lbound(batch, g + 1);

    float gcv = 0.f;
    if (e > s) {
        float m = -INFINITY;
        for (int n = s + lane; n < e; n += 64) m = fmaxf(m, gate[n]);
        #pragma unroll
        for (int off = 32; off; off >>= 1) m = fmaxf(m, __shfl_xor(m, off));
        float acc = 0.f, den = 0.f;
        for (int n = s; n < e; ++n) {
            float ev = expf(gate[n] - m);
            den += ev;
            acc += ev * bf2f(hn16[(size_t)n * 64 + lane]);
        }
        gcv = acc / den;
    }

    float sv = gcv * W_sp[lane];
    #pragma unroll
    for (int off = 32; off; off >>= 1) sv += __shfl_xor(sv, off);
    if (lane == 0) sg[g] = 1.f / (1.f + expf(-(sv + b_sp[0])));

    float pk = (lane < GFD) ? pocket[(size_t)g * GFD + lane] : 0.f;
    float pgv = b_fc1[lane];
    #pragma unroll 8
    for (int kk = 0; kk < 64; ++kk)
        pgv = fmaf(__shfl(gcv, kk), W_fc1[(64 + kk) * 64 + lane], pgv);
    #pragma unroll 8
    for (int kk = 0; kk < 32; ++kk)
        pgv = fmaf(__shfl(pk, kk), W_fc1[(128 + kk) * 64 + lane], pgv);
    pg[(size_t)g * 64 + lane] = pgv;
}

// ---------------- K4: MFMA head ----------------
__global__ __launch_bounds__(256, 4) void k4_mfma(
    const unsigned short* __restrict__ hn16, const int* __restrict__ batch,
    const float* __restrict__ pg, const float* __restrict__ sg,
    const unsigned short* __restrict__ W1aT, const unsigned short* __restrict__ W_npT,
    const float* __restrict__ b_np,
    float* __restrict__ out_np, float* __restrict__ out_stop)
{
    __shared__ __align__(16) float sF[4][32][FPAD];
    __shared__ int sB[128];

    const int t = threadIdx.x;
    const int wv = t >> 6, lane = t & 63;
    const int mr = lane & 31, half = lane >> 5;
    const int nb = blockIdx.x * 128;

    if (t < 128) {
        int n = nb + t;
        sB[t] = (n < NN) ? batch[n] : 0;
    }

    const int node = nb + wv * 32 + mr;

    f32x16 acc0, acc1;
    #pragma unroll
    for (int r = 0; r < 16; ++r) { acc0[r] = 0.f; acc1[r] = 0.f; }

    #pragma unroll
    for (int c = 0; c < 4; ++c) {
        short8v a;
        if (node < NN) {
            a = *(const short8v*)(hn16 + (size_t)node * 64 + c * 16 + half * 8);
        } else {
            #pragma unroll
            for (int q = 0; q < 8; ++q) a[q] = 0;
        }
        short8v b0 = *(const short8v*)(W1aT + (size_t)mr * 64        + c * 16 + half * 8);
        short8v b1 = *(const short8v*)(W1aT + (size_t)(mr + 32) * 64 + c * 16 + half * 8);
        acc0 = __builtin_amdgcn_mfma_f32_32x32x16_bf16(a, b0, acc0, 0, 0, 0);
        acc1 = __builtin_amdgcn_mfma_f32_32x32x16_bf16(a, b1, acc1, 0, 0, 0);
    }
    __syncthreads();

    #pragma unroll
    for (int r = 0; r < 16; ++r) {
        int row = (r & 3) + 8 * (r >> 2) + 4 * half;
        int g = sB[wv * 32 + row];
        float p0 = pg[(size_t)g * 64 + mr];
        float p1 = pg[(size_t)g * 64 + 32 + mr];
        sF[wv][row][mr]      = fmaxf(acc0[r] + p0, 0.f);
        sF[wv][row][32 + mr] = fmaxf(acc1[r] + p1, 0.f);
    }

    f32x16 acc2, acc3;
    #pragma unroll
    for (int r = 0; r < 16; ++r) { acc2[r] = 0.f; acc3[r] = 0.f; }

    #pragma unroll
    for (int c = 0; c < 4; ++c) {
        const float* fp = &sF[wv][mr][c * 16 + half * 8];
        float4 u0 = *(const float4*)(fp);
        float4 u1 = *(const float4*)(fp + 4);
        union { short8v v; unsigned u[4]; } A;
        A.u[0] = cvtpk(u0.x, u0.y); A.u[1] = cvtpk(u0.z, u0.w);
        A.u[2] = cvtpk(u1.x, u1.y); A.u[3] = cvtpk(u1.z, u1.w);
        short8v a = A.v;
        short8v b0 = *(const short8v*)(W_npT + (size_t)mr * 64        + c * 16 + half * 8);
        short8v b1 = *(const short8v*)(W_npT + (size_t)(mr + 32) * 64 + c * 16 + half * 8);
        acc2 = __builtin_amdgcn_mfma_f32_32x32x16_bf16(a, b0, acc2, 0, 0, 0);
        acc3 = __builtin_amdgcn_mfma_f32_32x32x16_bf16(a, b1, acc3, 0, 0, 0);
    }

    float bn1 = b_np[mr];
    float bn2 = (mr < 8) ? b_np[32 + mr] : 0.f;

    #pragma unroll
    for (int r = 0; r < 16; ++r) {
        int row = (r & 3) + 8 * (r >> 2) + 4 * half;
        int n = nb + wv * 32 + row;
        float v1 = acc2[r] + bn1;
        float v2 = acc3[r] + bn2;
        float m = (mr < 8) ? fmaxf(v1, v2) : v1;
        #pragma unroll
        for (int off = 16; off; off >>= 1) m = fmaxf(m, __shfl_xor(m, off));
        float s = expf(v1 - m) + ((mr < 8) ? expf(v2 - m) : 0.f);
        #pragma unroll
        for (int off = 16; off; off >>= 1) s += __shfl_xor(s, off);
        float ls = m + logf(s);
        if (n < NN) {
            out_np[(size_t)n * CC + mr] = v1 - ls;
            if (mr < 8) out_np[(size_t)n * CC + 32 + mr] = v2 - ls;
            if (mr == 0) out_stop[n] = sg[sB[wv * 32 + row]];
        }
    }
}

extern "C" void kernel_launch(void* const* d_in, const int* in_sizes, int n_in,
                              void* d_out, int out_size, void* d_ws, size_t ws_size,
                              hipStream_t stream)
{
    (void)in_sizes; (void)n_in; (void)out_size;
    const float* x        = (const float*)d_in[0];
    const int*   ei       = (const int*)d_in[1];
    const float* ea       = (const float*)d_in[2];
    const int*   batch    = (const int*)d_in[3];
    const float* pocket   = (const float*)d_in[4];
    const float* W_e1     = (const float*)d_in[5];
    const float* b_e1     = (const float*)d_in[6];
    const float* W_e2     = (const float*)d_in[7];
    const float* b_e2     = (const float*)d_in[8];
    const float* root     = (const float*)d_in[9];
    const float* conv_b   = (const float*)d_in[10];
    const float* Wg       = (const float*)d_in[11];
    const float* bg       = (const float*)d_in[12];
    const float* W_fc1    = (const float*)d_in[13];
    const float* b_fc1    = (const float*)d_in[14];
    const float* W_np     = (const float*)d_in[15];
    const float* b_np     = (const float*)d_in[16];
    const float* W_sp     = (const float*)d_in[17];
    const float* b_sp     = (const float*)d_in[18];

    char* wsb = (char*)d_ws;
    float* agg    = (float*)wsb;                         // NN*64 (atomic fallback only)
    int*   base   = (int*)(agg + (size_t)NN * 64);       // NN+4
    int*   bsum   = base + NN + 4;                       // 256
    int*   cursor = bsum + 256;                          // NN
    int*   rank   = cursor + NN;                         // EE
    float* gate   = (float*)(rank + EE);                 // NN
    float* pg     = gate + NN;                           // GG*64
    float* sg     = pg + (size_t)GG * 64;                // GG
    unsigned short* hn16  = (unsigned short*)(sg + GG);  // NN*64 u16
    unsigned short* W2c   = hn16 + (size_t)NN * 64;      // W2SZ
    unsigned short* W1aT  = W2c + W2SZ;                  // 4096
    unsigned short* W_npT = W1aT + 4096;                 // 4096
    unsigned short* W1e   = W_npT + 4096;                // 512
    size_t head = (size_t)((char*)(W1e + 512) - wsb);
    size_t msg_off = (head + 255) & ~(size_t)255;
    unsigned* msg16 = (unsigned*)(wsb + msg_off);        // EE*32 u32
    size_t need = msg_off + (size_t)EE * 32 * sizeof(unsigned);
    const bool twophase = (ws_size >= need);

    k0_prep<<<(W2SZ + 8704 + NN + 255) / 256, 256, 0, stream>>>(
        W_e2, b_e2, W_fc1, W_np, W_e1, W2c, W1aT, W_npT, W1e, cursor);

    kE_local<<<(EE + 255) / 256, 256, 0, stream>>>(ei, cursor, rank);
    kB_scan1<<<NBLK, 256, 0, stream>>>(cursor, base, bsum);
    kC_scan2<<<1, 256, 0, stream>>>(bsum);

    if (twophase) {
        k1_mfma<true><<<(EE + 255) / 256, 256, 0, stream>>>(
            x, ei, ea, W1e, b_e1, W2c, rank, base, bsum, msg16, agg);
        k2_red<<<NN / 4, 256, 0, stream>>>(msg16, base, bsum, x, root, conv_b,
                                           hn16, Wg, bg, gate);
    } else {
        hipMemsetAsync(agg, 0, (size_t)NN * 64 * sizeof(float), stream);
        k1_mfma<false><<<(EE + 255) / 256, 256, 0, stream>>>(
            x, ei, ea, W1e, b_e1, W2c, rank, base, bsum, msg16, agg);
        k2_node<<<NN / 4, 256, 0, stream>>>(agg, base, bsum, x, root, conv_b,
                                            hn16, Wg, bg, gate);
    }

    k3_pool<<<GG, 64, 0, stream>>>(gate, batch, hn16, pocket, W_fc1, b_fc1, W_sp, b_sp, pg, sg);

    float* out_np   = (float*)d_out;
    float* out_stop = out_np + (size_t)NN * CC;
    k4_mfma<<<(NN + 127) / 128, 256, 0, stream>>>(hn16, batch, pg, sg, W1aT, W_npT, b_np,
                                                  out_np, out_stop);
}

// Round 13
// 255.091 us; speedup vs baseline: 1.5219x; 1.0188x over previous
//
#include <hip/hip_runtime.h>
#include <hip/hip_bf16.h>
#include <math.h>

#define NN 150000
#define EE 600000
#define GG 5000
#define NI 16
#define EI 8
#define GFD 32
#define HH 64
#define CC 40

#define W2SZ (68 * 1024)   // 68 chunks (64 real + bias@64 + 3 zero) x 64 rows x 16 k, chunk-major
#define EHS 72             // u16 stride of sEHT2 rows (144B: 16B-aligned, 4-way max on b128)
#define FPAD 68
#define NBLK ((NN + 1023) / 1024)

typedef __attribute__((ext_vector_type(8))) short short8v;
typedef __attribute__((ext_vector_type(8))) unsigned short ushort8v;
typedef __attribute__((ext_vector_type(16))) float f32x16;
typedef __attribute__((ext_vector_type(2))) float f32x2;

__device__ __forceinline__ unsigned short f2bf(float f) {
    __hip_bfloat16 h = __float2bfloat16(f);
    return __builtin_bit_cast(unsigned short, h);
}
__device__ __forceinline__ float bf2f(unsigned short u) {
    return __uint_as_float(((unsigned)u) << 16);
}
__device__ __forceinline__ unsigned cvtpk(float lo, float hi) {
    unsigned r;
    asm("v_cvt_pk_bf16_f32 %0, %1, %2" : "=v"(r) : "v"(lo), "v"(hi));
    return r;
}
__device__ __forceinline__ f32x2 pkmul(f32x2 a, f32x2 b) {
    f32x2 p;
    asm("v_pk_mul_f32 %0, %1, %2" : "=v"(p) : "v"(a), "v"(b));
    return p;
}
__device__ __forceinline__ short8v zfrag(float eh, const f32x2 (&xs2)[4]) {
    f32x2 ehp; ehp[0] = eh; ehp[1] = eh;
    union { short8v v; unsigned u[4]; } A;
    #pragma unroll
    for (int q = 0; q < 4; ++q) {
        f32x2 p = pkmul(ehp, xs2[q]);
        A.u[q] = cvtpk(p[0], p[1]);
    }
    return A.v;
}
__device__ __forceinline__ short8v xfrag(const f32x2 (&xs2)[4]) {
    union { short8v v; unsigned u[4]; } A;
    #pragma unroll
    for (int q = 0; q < 4; ++q)
        A.u[q] = cvtpk(xs2[q][0], xs2[q][1]);
    return A.v;
}

// ---------------- K0: prep bf16 weight views + zero cursor ----------------
__global__ void k0_prep(const float* __restrict__ W_e2, const float* __restrict__ b_e2,
                        const float* __restrict__ W_fc1, const float* __restrict__ W_np,
                        const float* __restrict__ W_e1,
                        unsigned short* __restrict__ W2c,
                        unsigned short* __restrict__ W1aT,
                        unsigned short* __restrict__ W_npT,
                        unsigned short* __restrict__ W1e,
                        int* __restrict__ cursor)
{
    int idx = blockIdx.x * 256 + threadIdx.x;
    if (idx < W2SZ) {
        int c = idx >> 10, rem = idx & 1023;
        int r = rem >> 4, kk = rem & 15;
        float v = 0.f;
        if (c < 64)       v = W_e2[c * 1024 + kk * 64 + r];
        else if (c == 64) v = b_e2[kk * 64 + r];
        W2c[idx] = f2bf(v);
    } else if (idx < W2SZ + 4096) {
        int i = idx - W2SZ;
        int h = i >> 6, k = i & 63;
        W1aT[i] = f2bf(W_fc1[k * 64 + h]);
    } else if (idx < W2SZ + 8192) {
        int i = idx - W2SZ - 4096;
        int c = i >> 6, h = i & 63;
        W_npT[i] = f2bf(c < CC ? W_np[h * CC + c] : 0.f);
    } else if (idx < W2SZ + 8704) {
        int i = idx - W2SZ - 8192;   // W1e[col][q] = W_e1[q][col]
        int col = i >> 3, q = i & 7;
        W1e[i] = f2bf(W_e1[q * 64 + col]);
    } else if (idx < W2SZ + 8704 + NN) {
        cursor[idx - W2SZ - 8704] = 0;
    }
}

// ---------------- kE_local: local rank within dst + counts ----------------
__global__ void kE_local(const int* __restrict__ ei, int* __restrict__ cursor,
                         int* __restrict__ rank)
{
    int e = blockIdx.x * 256 + threadIdx.x;
    if (e < EE) rank[e] = atomicAdd(&cursor[ei[EE + e]], 1);
}

// ---------------- scan of counts -> base (block-local; consumers add bsum[i>>10]) ----------------
__global__ void kB_scan1(const int* __restrict__ cnt, int* __restrict__ base,
                         int* __restrict__ bsum)
{
    __shared__ int sS[256];
    int b = blockIdx.x, t = threadIdx.x;
    int i0 = b * 1024 + t * 4;
    int v0 = (i0 + 0 < NN) ? cnt[i0 + 0] : 0;
    int v1 = (i0 + 1 < NN) ? cnt[i0 + 1] : 0;
    int v2 = (i0 + 2 < NN) ? cnt[i0 + 2] : 0;
    int v3 = (i0 + 3 < NN) ? cnt[i0 + 3] : 0;
    int tot = v0 + v1 + v2 + v3;
    sS[t] = tot;
    __syncthreads();
    int acc = tot;
    for (int off = 1; off < 256; off <<= 1) {
        int xv = (t >= off) ? sS[t - off] : 0;
        __syncthreads();
        acc += xv;
        sS[t] = acc;
        __syncthreads();
    }
    int run = acc - tot;
    if (i0 + 0 < NN) base[i0 + 0] = run; run += v0;
    if (i0 + 1 < NN) base[i0 + 1] = run; run += v1;
    if (i0 + 2 < NN) base[i0 + 2] = run; run += v2;
    if (i0 + 3 < NN) base[i0 + 3] = run;
    if (t == 255) bsum[b] = acc;
}

__global__ void kC_scan2(int* __restrict__ bsum)
{
    __shared__ int sS[256];
    int t = threadIdx.x;
    int v = (t < NBLK) ? bsum[t] : 0;
    sS[t] = v;
    __syncthreads();
    int acc = v;
    for (int off = 1; off < 256; off <<= 1) {
        int xv = (t >= off) ? sS[t - off] : 0;
        __syncthreads();
        acc += xv;
        sS[t] = acc;
        __syncthreads();
    }
    if (t < NBLK) bsum[t] = acc - v;   // exclusive
}

// ---------------- K1: M=32 wave-tiles; MFMA edge MLP + MFMA z-GEMM ----------------
template<bool TWOPHASE>
__global__ __launch_bounds__(256, 5) void k1_mfma(
    const float* __restrict__ x, const int* __restrict__ ei,
    const float* __restrict__ ea,
    const unsigned short* __restrict__ W1e, const float* __restrict__ b_e1,
    const unsigned short* __restrict__ W2c,
    const int* __restrict__ rank, const int* __restrict__ base,
    const int* __restrict__ bsum,
    unsigned* __restrict__ msg16, float* __restrict__ agg)
{
    __shared__ unsigned short sEHT2[128][EHS];   // [edge][k] bf16, transposed
    __shared__ int sIdx[128];

    const int t = threadIdx.x;
    const long long eb = (long long)blockIdx.x * 128;

    const int lane = t & 63;
    const int w = t >> 6;
    const int mr = lane & 31;
    const int half = lane >> 5;
    const int mb2 = w * 32;      // wave's 32-edge base

    if (t < 128) {
        long long ge = eb + t;
        if (ge < EE) {
            int d = ei[EE + ge];
            sIdx[t] = TWOPHASE ? (base[d] + bsum[d >> 10] + rank[ge]) : d;
        } else {
            sIdx[t] = -1;
        }
    }

    // ---- edge MLP layer 1 via MFMA (wave's own 32 edges) -> sEHT2 transposed ----
    {
        short8v bW0, bW1;
        if (half == 0) {
            bW0 = *(const short8v*)(W1e + (size_t)mr * 8);
            bW1 = *(const short8v*)(W1e + (size_t)(32 + mr) * 8);
        } else {
            #pragma unroll
            for (int q = 0; q < 8; ++q) { bW0[q] = 0; bW1[q] = 0; }
        }
        float bias0 = b_e1[mr];
        float bias1 = b_e1[32 + mr];
        long long ge = eb + mb2 + mr;
        short8v a;
        if (half == 0 && ge < EE) {
            const float4* eap = (const float4*)(ea + ge * EI);
            float4 u0 = eap[0], u1 = eap[1];
            union { short8v v; unsigned u[4]; } A;
            A.u[0] = cvtpk(u0.x, u0.y); A.u[1] = cvtpk(u0.z, u0.w);
            A.u[2] = cvtpk(u1.x, u1.y); A.u[3] = cvtpk(u1.z, u1.w);
            a = A.v;
        } else {
            #pragma unroll
            for (int q = 0; q < 8; ++q) a[q] = 0;
        }
        #pragma unroll
        for (int n = 0; n < 2; ++n) {
            f32x16 c_;
            #pragma unroll
            for (int r = 0; r < 16; ++r) c_[r] = 0.f;
            c_ = __builtin_amdgcn_mfma_f32_32x32x16_bf16(a, n ? bW1 : bW0, c_, 0, 0, 0);
            int kcol = n * 32 + mr;
            float bias = n ? bias1 : bias0;
            #pragma unroll
            for (int r = 0; r < 16; ++r) {
                int row = (r & 3) + 8 * (r >> 2) + 4 * half;
                sEHT2[mb2 + row][kcol] = f2bf(fmaxf(c_[r] + bias, 0.f));
            }
        }
    }

    // ---- per-lane xs gather (1 edge) ----
    f32x2 xs[4];
    {
        long long ge = eb + mb2 + mr;
        if (ge < EE) {
            int s0 = ei[ge];
            const float4* xp = (const float4*)(x + (size_t)s0 * NI + half * 8);
            float4 u0 = xp[0], u1 = xp[1];
            xs[0][0]=u0.x; xs[0][1]=u0.y; xs[1][0]=u0.z; xs[1][1]=u0.w;
            xs[2][0]=u1.x; xs[2][1]=u1.y; xs[3][0]=u1.z; xs[3][1]=u1.w;
        } else {
            #pragma unroll
            for (int q = 0; q < 4; ++q) { xs[q][0] = 0.f; xs[q][1] = 0.f; }
        }
    }
    __syncthreads();

    f32x16 acc0, acc1;
    #pragma unroll
    for (int r = 0; r < 16; ++r) { acc0[r] = 0.f; acc1[r] = 0.f; }

    // chunk-major B: per chunk, wave's two loads cover the chunk's contiguous 2KB
    const unsigned short* Bq0 = W2c + mr * 16 + half * 8;
    const unsigned short* Bq1 = Bq0 + 512;

    short8v bA0 = *(const short8v*)(Bq0);
    short8v bA1 = *(const short8v*)(Bq1);
    short8v bB0 = *(const short8v*)(Bq0 + 1024);
    short8v bB1 = *(const short8v*)(Bq1 + 1024);

    const unsigned short* ehp = &sEHT2[mb2 + mr][0];
    ushort8v ehCur = *(const ushort8v*)(ehp);

    #pragma unroll 1
    for (int cb = 0; cb < 64; cb += 8) {
        ushort8v ehNext = *(const ushort8v*)(ehp + cb + 8);   // cb=56 reads pad cols (unused)
        #pragma unroll
        for (int j = 0; j < 8; j += 2) {
            int c = cb + j;
            {
                short8v n0 = *(const short8v*)(Bq0 + (c + 2) * 1024);
                short8v n1 = *(const short8v*)(Bq1 + (c + 2) * 1024);
                short8v a = zfrag(bf2f(ehCur[j]), xs);
                __builtin_amdgcn_s_setprio(1);
                acc0 = __builtin_amdgcn_mfma_f32_32x32x16_bf16(a, bA0, acc0, 0, 0, 0);
                acc1 = __builtin_amdgcn_mfma_f32_32x32x16_bf16(a, bA1, acc1, 0, 0, 0);
                __builtin_amdgcn_s_setprio(0);
                bA0 = n0; bA1 = n1;
            }
            {
                short8v n0 = *(const short8v*)(Bq0 + (c + 3) * 1024);
                short8v n1 = *(const short8v*)(Bq1 + (c + 3) * 1024);
                short8v a = zfrag(bf2f(ehCur[j + 1]), xs);
                __builtin_amdgcn_s_setprio(1);
                acc0 = __builtin_amdgcn_mfma_f32_32x32x16_bf16(a, bB0, acc0, 0, 0, 0);
                acc1 = __builtin_amdgcn_mfma_f32_32x32x16_bf16(a, bB1, acc1, 0, 0, 0);
                __builtin_amdgcn_s_setprio(0);
                bB0 = n0; bB1 = n1;
            }
        }
        ehCur = ehNext;
    }
    // bias chunk c=64: eh = 1 -> A = bf16(xs); B in bA (prefetched at c=62)
    {
        short8v a = xfrag(xs);
        __builtin_amdgcn_s_setprio(1);
        acc0 = __builtin_amdgcn_mfma_f32_32x32x16_bf16(a, bA0, acc0, 0, 0, 0);
        acc1 = __builtin_amdgcn_mfma_f32_32x32x16_bf16(a, bA1, acc1, 0, 0, 0);
        __builtin_amdgcn_s_setprio(0);
    }

    // ---- epilogue ----
    #pragma unroll
    for (int r = 0; r < 16; ++r) {
        int row = (r & 3) + 8 * (r >> 2) + 4 * half;
        int i0 = sIdx[mb2 + row];
        if (TWOPHASE) {
            if (i0 >= 0) msg16[(size_t)i0 * 32 + mr] = cvtpk(acc0[r], acc1[r]);
        } else {
            if (i0 >= 0) {
                atomicAdd(&agg[(size_t)i0 * 64 + mr],      acc0[r]);
                atomicAdd(&agg[(size_t)i0 * 64 + 32 + mr], acc1[r]);
            }
        }
    }
}

// ---------------- K2 (two-phase): stream-reduce bf16 msg16 + mean + root + relu + gate ----------------
__global__ __launch_bounds__(256) void k2_red(
    const unsigned* __restrict__ msg16, const int* __restrict__ base,
    const int* __restrict__ bsum,
    const float* __restrict__ x, const float* __restrict__ root,
    const float* __restrict__ conv_bias,
    unsigned short* __restrict__ hn16,
    const float* __restrict__ Wg, const float* __restrict__ bg,
    float* __restrict__ gate)
{
    __shared__ float sroot[16][64];
    int t = threadIdx.x;
    #pragma unroll
    for (int q = 0; q < 4; ++q) {
        int i = q * 256 + t;
        sroot[i >> 6][i & 63] = root[i];
    }
    __syncthreads();

    int n = blockIdx.x * 4 + (t >> 6);
    int l = t & 63;
    int mr = l & 31, so = l >> 5;
    int s = base[n] + bsum[n >> 10];
    int e = (n == NN - 1) ? EE : base[n + 1] + bsum[(n + 1) >> 10];

    float alo = 0.f, ahi = 0.f;
    int sl = s + so;
    for (; sl + 2 < e; sl += 4) {
        unsigned u0 = msg16[(size_t)sl * 32 + mr];
        unsigned u1 = msg16[(size_t)(sl + 2) * 32 + mr];
        alo += __uint_as_float(u0 << 16) + __uint_as_float(u1 << 16);
        ahi += __uint_as_float(u0 & 0xFFFF0000u) + __uint_as_float(u1 & 0xFFFF0000u);
    }
    if (sl < e) {
        unsigned u = msg16[(size_t)sl * 32 + mr];
        alo += __uint_as_float(u << 16);
        ahi += __uint_as_float(u & 0xFFFF0000u);
    }
    alo += __shfl_xor(alo, 32);
    ahi += __shfl_xor(ahi, 32);
    float acc = (l < 32) ? alo : ahi;

    float inv = 1.0f / fmaxf((float)(e - s), 1.0f);
    float v = acc * inv + conv_bias[l];
    float xv = (l < 16) ? x[(size_t)n * NI + l] : 0.f;
    #pragma unroll
    for (int i = 0; i < 16; ++i)
        v = fmaf(__shfl(xv, i), sroot[i][l], v);
    v = fmaxf(v, 0.f);
    hn16[(size_t)n * 64 + l] = f2bf(v);

    float gv = v * Wg[l];
    #pragma unroll
    for (int off = 32; off; off >>= 1) gv += __shfl_xor(gv, off);
    if (l == 0) gate[n] = gv + bg[0];
}

// ---------------- K2 (fallback): mean + root + relu over agg ----------------
__global__ __launch_bounds__(256) void k2_node(
    const float* __restrict__ agg, const int* __restrict__ base,
    const int* __restrict__ bsum,
    const float* __restrict__ x, const float* __restrict__ root,
    const float* __restrict__ conv_bias,
    unsigned short* __restrict__ hn16,
    const float* __restrict__ Wg, const float* __restrict__ bg,
    float* __restrict__ gate)
{
    int t = threadIdx.x;
    int n = blockIdx.x * 4 + (t >> 6);
    int h = t & 63;
    int s = base[n] + bsum[n >> 10];
    int e = (n == NN - 1) ? EE : base[n + 1] + bsum[(n + 1) >> 10];
    float inv = 1.0f / fmaxf((float)(e - s), 1.0f);
    float v = agg[(size_t)n * 64 + h] * inv + conv_bias[h];
    const float* xp = x + (size_t)n * NI;
    #pragma unroll
    for (int i = 0; i < NI; ++i) v += xp[i] * root[i * 64 + h];
    v = fmaxf(v, 0.f);
    hn16[(size_t)n * 64 + h] = f2bf(v);
    float gv = v * Wg[h];
    #pragma unroll
    for (int off = 32; off; off >>= 1) gv += __shfl_xor(gv, off);
    if (h == 0) gate[n] = gv + bg[0];
}

// ---------------- K3: per-graph pooling + pg/sg precompute ----------------
__device__ __forceinline__ int lbound(const int* __restrict__ b, int v) {
    int lo = 0, hi = NN;
    while (lo < hi) { int mid = (lo + hi) >> 1; if (b[mid] < v) lo = mid + 1; else hi = mid; }
    return lo;
}

__global__ __launch_bounds__(64) void k3_pool(
    const float* __restrict__ gate, const int* __restrict__ batch,
    const unsigned short* __restrict__ hn16, const float* __restrict__ pocket,
    const float* __restrict__ W_fc1, const float* __restrict__ b_fc1,
    const float* __restrict__ W_sp, const float* __restrict__ b_sp,
    float* __restrict__ pg, float* __restrict__ sg)
{
    int g = blockIdx.x;
    int lane = threadIdx.x;
    int s = lbound(batch, g);
    int e = lbound(batch, g + 1);

    float gcv = 0.f;
    if (e > s) {
        float m = -INFINITY;
        for (int n = s + lane; n < e; n += 64) m = fmaxf(m, gate[n]);
        #pragma unroll
        for (int off = 32; off; off >>= 1) m = fmaxf(m, __shfl_xor(m, off));
        float acc = 0.f, den = 0.f;
        int n = s;
        for (; n + 2 <= e; n += 2) {
            float e0 = expf(gate[n] - m);
            float e1 = expf(gate[n + 1] - m);
            float h0 = bf2f(hn16[(size_t)n * 64 + lane]);
            float h1 = bf2f(hn16[(size_t)(n + 1) * 64 + lane]);
            den += e0 + e1;
            acc = fmaf(e0, h0, acc);
            acc = fmaf(e1, h1, acc);
        }
        if (n < e) {
            float ev = expf(gate[n] - m);
            den += ev;
            acc = fmaf(ev, bf2f(hn16[(size_t)n * 64 + lane]), acc);
        }
        gcv = acc / den;
    }

    float sv = gcv * W_sp[lane];
    #pragma unroll
    for (int off = 32; off; off >>= 1) sv += __shfl_xor(sv, off);
    if (lane == 0) sg[g] = 1.f / (1.f + expf(-(sv + b_sp[0])));

    float pk = (lane < GFD) ? pocket[(size_t)g * GFD + lane] : 0.f;
    float pgv = b_fc1[lane];
    #pragma unroll 8
    for (int kk = 0; kk < 64; ++kk)
        pgv = fmaf(__shfl(gcv, kk), W_fc1[(64 + kk) * 64 + lane], pgv);
    #pragma unroll 8
    for (int kk = 0; kk < 32; ++kk)
        pgv = fmaf(__shfl(pk, kk), W_fc1[(128 + kk) * 64 + lane], pgv);
    pg[(size_t)g * 64 + lane] = pgv;
}

// ---------------- K4: MFMA head ----------------
__global__ __launch_bounds__(256, 4) void k4_mfma(
    const unsigned short* __restrict__ hn16, const int* __restrict__ batch,
    const float* __restrict__ pg, const float* __restrict__ sg,
    const unsigned short* __restrict__ W1aT, const unsigned short* __restrict__ W_npT,
    const float* __restrict__ b_np,
    float* __restrict__ out_np, float* __restrict__ out_stop)
{
    __shared__ __align__(16) float sF[4][32][FPAD];
    __shared__ int sB[128];

    const int t = threadIdx.x;
    const int wv = t >> 6, lane = t & 63;
    const int mr = lane & 31, half = lane >> 5;
    const int nb = blockIdx.x * 128;

    if (t < 128) {
        int n = nb + t;
        sB[t] = (n < NN) ? batch[n] : 0;
    }

    const int node = nb + wv * 32 + mr;

    f32x16 acc0, acc1;
    #pragma unroll
    for (int r = 0; r < 16; ++r) { acc0[r] = 0.f; acc1[r] = 0.f; }

    #pragma unroll
    for (int c = 0; c < 4; ++c) {
        short8v a;
        if (node < NN) {
            a = *(const short8v*)(hn16 + (size_t)node * 64 + c * 16 + half * 8);
        } else {
            #pragma unroll
            for (int q = 0; q < 8; ++q) a[q] = 0;
        }
        short8v b0 = *(const short8v*)(W1aT + (size_t)mr * 64        + c * 16 + half * 8);
        short8v b1 = *(const short8v*)(W1aT + (size_t)(mr + 32) * 64 + c * 16 + half * 8);
        acc0 = __builtin_amdgcn_mfma_f32_32x32x16_bf16(a, b0, acc0, 0, 0, 0);
        acc1 = __builtin_amdgcn_mfma_f32_32x32x16_bf16(a, b1, acc1, 0, 0, 0);
    }
    __syncthreads();

    #pragma unroll
    for (int r = 0; r < 16; ++r) {
        int row = (r & 3) + 8 * (r >> 2) + 4 * half;
        int g = sB[wv * 32 + row];
        float p0 = pg[(size_t)g * 64 + mr];
        float p1 = pg[(size_t)g * 64 + 32 + mr];
        sF[wv][row][mr]      = fmaxf(acc0[r] + p0, 0.f);
        sF[wv][row][32 + mr] = fmaxf(acc1[r] + p1, 0.f);
    }

    f32x16 acc2, acc3;
    #pragma unroll
    for (int r = 0; r < 16; ++r) { acc2[r] = 0.f; acc3[r] = 0.f; }

    #pragma unroll
    for (int c = 0; c < 4; ++c) {
        const float* fp = &sF[wv][mr][c * 16 + half * 8];
        float4 u0 = *(const float4*)(fp);
        float4 u1 = *(const float4*)(fp + 4);
        union { short8v v; unsigned u[4]; } A;
        A.u[0] = cvtpk(u0.x, u0.y); A.u[1] = cvtpk(u0.z, u0.w);
        A.u[2] = cvtpk(u1.x, u1.y); A.u[3] = cvtpk(u1.z, u1.w);
        short8v a = A.v;
        short8v b0 = *(const short8v*)(W_npT + (size_t)mr * 64        + c * 16 + half * 8);
        short8v b1 = *(const short8v*)(W_npT + (size_t)(mr + 32) * 64 + c * 16 + half * 8);
        acc2 = __builtin_amdgcn_mfma_f32_32x32x16_bf16(a, b0, acc2, 0, 0, 0);
        acc3 = __builtin_amdgcn_mfma_f32_32x32x16_bf16(a, b1, acc3, 0, 0, 0);
    }

    float bn1 = b_np[mr];
    float bn2 = (mr < 8) ? b_np[32 + mr] : 0.f;

    #pragma unroll
    for (int r = 0; r < 16; ++r) {
        int row = (r & 3) + 8 * (r >> 2) + 4 * half;
        int n = nb + wv * 32 + row;
        float v1 = acc2[r] + bn1;
        float v2 = acc3[r] + bn2;
        float m = (mr < 8) ? fmaxf(v1, v2) : v1;
        #pragma unroll
        for (int off = 16; off; off >>= 1) m = fmaxf(m, __shfl_xor(m, off));
        float s = expf(v1 - m) + ((mr < 8) ? expf(v2 - m) : 0.f);
        #pragma unroll
        for (int off = 16; off; off >>= 1) s += __shfl_xor(s, off);
        float ls = m + logf(s);
        if (n < NN) {
            out_np[(size_t)n * CC + mr] = v1 - ls;
            if (mr < 8) out_np[(size_t)n * CC + 32 + mr] = v2 - ls;
            if (mr == 0) out_stop[n] = sg[sB[wv * 32 + row]];
        }
    }
}

extern "C" void kernel_launch(void* const* d_in, const int* in_sizes, int n_in,
                              void* d_out, int out_size, void* d_ws, size_t ws_size,
                              hipStream_t stream)
{
    (void)in_sizes; (void)n_in; (void)out_size;
    const float* x        = (const float*)d_in[0];
    const int*   ei       = (const int*)d_in[1];
    const float* ea       = (const float*)d_in[2];
    const int*   batch    = (const int*)d_in[3];
    const float* pocket   = (const float*)d_in[4];
    const float* W_e1     = (const float*)d_in[5];
    const float* b_e1     = (const float*)d_in[6];
    const float* W_e2     = (const float*)d_in[7];
    const float* b_e2     = (const float*)d_in[8];
    const float* root     = (const float*)d_in[9];
    const float* conv_b   = (const float*)d_in[10];
    const float* Wg       = (const float*)d_in[11];
    const float* bg       = (const float*)d_in[12];
    const float* W_fc1    = (const float*)d_in[13];
    const float* b_fc1    = (const float*)d_in[14];
    const float* W_np     = (const float*)d_in[15];
    const float* b_np     = (const float*)d_in[16];
    const float* W_sp     = (const float*)d_in[17];
    const float* b_sp     = (const float*)d_in[18];

    char* wsb = (char*)d_ws;
    float* agg    = (float*)wsb;                         // NN*64 (atomic fallback only)
    int*   base   = (int*)(agg + (size_t)NN * 64);       // NN+4
    int*   bsum   = base + NN + 4;                       // 256
    int*   cursor = bsum + 256;                          // NN
    int*   rank   = cursor + NN;                         // EE
    float* gate   = (float*)(rank + EE);                 // NN
    float* pg     = gate + NN;                           // GG*64
    float* sg     = pg + (size_t)GG * 64;                // GG
    unsigned short* hn16  = (unsigned short*)(sg + GG);  // NN*64 u16
    unsigned short* W2c   = hn16 + (size_t)NN * 64;      // W2SZ
    unsigned short* W1aT  = W2c + W2SZ;                  // 4096
    unsigned short* W_npT = W1aT + 4096;                 // 4096
    unsigned short* W1e   = W_npT + 4096;                // 512
    size_t head = (size_t)((char*)(W1e + 512) - wsb);
    size_t msg_off = (head + 255) & ~(size_t)255;
    unsigned* msg16 = (unsigned*)(wsb + msg_off);        // EE*32 u32
    size_t need = msg_off + (size_t)EE * 32 * sizeof(unsigned);
    const bool twophase = (ws_size >= need);

    k0_prep<<<(W2SZ + 8704 + NN + 255) / 256, 256, 0, stream>>>(
        W_e2, b_e2, W_fc1, W_np, W_e1, W2c, W1aT, W_npT, W1e, cursor);

    kE_local<<<(EE + 255) / 256, 256, 0, stream>>>(ei, cursor, rank);
    kB_scan1<<<NBLK, 256, 0, stream>>>(cursor, base, bsum);
    kC_scan2<<<1, 256, 0, stream>>>(bsum);

    if (twophase) {
        k1_mfma<true><<<(EE + 127) / 128, 256, 0, stream>>>(
            x, ei, ea, W1e, b_e1, W2c, rank, base, bsum, msg16, agg);
        k2_red<<<NN / 4, 256, 0, stream>>>(msg16, base, bsum, x, root, conv_b,
                                           hn16, Wg, bg, gate);
    } else {
        hipMemsetAsync(agg, 0, (size_t)NN * 64 * sizeof(float), stream);
        k1_mfma<false><<<(EE + 127) / 128, 256, 0, stream>>>(
            x, ei, ea, W1e, b_e1, W2c, rank, base, bsum, msg16, agg);
        k2_node<<<NN / 4, 256, 0, stream>>>(agg, base, bsum, x, root, conv_b,
                                            hn16, Wg, bg, gate);
    }

    k3_pool<<<GG, 64, 0, stream>>>(gate, batch, hn16, pocket, W_fc1, b_fc1, W_sp, b_sp, pg, sg);

    float* out_np   = (float*)d_out;
    float* out_stop = out_np + (size_t)NN * CC;
    k4_mfma<<<(NN + 127) / 128, 256, 0, stream>>>(hn16, batch, pg, sg, W1aT, W_npT, b_np,
                                                  out_np, out_stop);
}